// Round 9
// baseline (231.148 us; speedup 1.0000x reference)
//
#include <hip/hip_runtime.h>
#include <hip/hip_bf16.h>
#include <math.h>

#define NN 10000
#define NE 100000
#define NBLK2 ((NE + 63) / 64)   // 1563 blocks, 64 edges (4 waves x 16)

typedef __attribute__((ext_vector_type(4))) float f32x4;
typedef __attribute__((ext_vector_type(8))) short short8;

static constexpr float C_TANH  = 1.5927f;
static constexpr float SQ3     = 1.7320508075688772f;
static constexpr float H_SCALE = 0.4472135954999579f;   // C_RELU/sqrt(10)
// output-region scales with 1/sqrt(16) folded in
static constexpr float A0Q   = 0.11785113019775793f * 0.25f;  // sqrt(1/72)/4
static constexpr float A0S3Q = 0.06804138174397717f * 0.25f;  // sqrt(1/216)/4
static constexpr float B0Q   = 0.20412414523193154f * 0.25f;  // sqrt(1/24)/4
static constexpr float B0S3Q = 0.11785113019775793f * 0.25f;  // sqrt(1/72)/4
static constexpr float S32 = 0.1767766952966369f;
static constexpr float S16 = 0.25f;
static constexpr float S8  = 0.3535533905932738f;

__device__ __forceinline__ unsigned short f2bf(float f) {
  union { float f; unsigned u; } cv; cv.f = f;
  unsigned r = cv.u + 0x7fffu + ((cv.u >> 16) & 1u);
  return (unsigned short)(r >> 16);
}
__device__ __forceinline__ float bf2f(unsigned short s) {
  return __uint_as_float(((unsigned)s) << 16);
}

// ---------------------------------------------------------------------------
// Prep: 4 frag-linear bf16 weight blobs (112KB) in d_ws (unchanged since r3).
// ---------------------------------------------------------------------------
__global__ void prep2_kernel(const float* __restrict__ fc1_w2,
                             const float* __restrict__ fc2_w2,
                             unsigned short* __restrict__ wb) {
  int t = blockIdx.x * blockDim.x + threadIdx.x;
  if (t >= 112 * 64) return;
  int lane = t & 63, blk = t >> 6;
  int grp = lane >> 4, c = lane & 15;
  unsigned short* dst = wb + (size_t)blk * 512 + lane * 8;
  int gemm, s, nt;
  if (blk < 72)       { gemm = 0; s = blk >> 1;        nt = blk & 1; }
  else if (blk < 84)  { gemm = 1; s = blk - 72;        nt = 0; }
  else if (blk < 108) { gemm = 2; s = (blk - 84) >> 1; nt = (blk - 84) & 1; }
  else                { gemm = 3; s = blk - 108;       nt = 0; }
  int n = nt * 16 + c;
  #pragma unroll
  for (int j = 0; j < 8; ++j) {
    int K = 32 * s + grp * 8 + j;
    int u = K >> 4, k = K & 15;
    float v = 0.f;
    if (gemm == 0) {
      if (n < 16) v = (u < 48) ? A0Q   * fc1_w2[k * 2304 + u * 16 + n]
                               : A0S3Q * fc1_w2[k * 2304 + 1152 + (u - 48) * 16 + n];
      else if (n < 24) { int w = n - 16;
        v = (u < 48) ? A0Q   * fc1_w2[k * 2304 + 768 + u * 8 + w]
                     : A0S3Q * fc1_w2[k * 2304 + 1536 + (u - 48) * 8 + w];
      } else { int w = n - 24;
        v = (u < 48) ? A0Q * fc1_w2[k * 2304 + 1728 + u * 8 + w] : 0.f;
      }
    } else if (gemm == 1) {
      v = (n < 8) ? A0Q * fc1_w2[k * 2304 + 2112 + u * 8 + n] : 0.f;
    } else if (gemm == 2) {
      if (u < 16) {
        if (n < 16)      v = B0Q * fc2_w2[k * 576 + u * 16 + n];
        else if (n < 24) v = B0Q * fc2_w2[k * 576 + 384 + u * 8 + (n - 16)];
      } else {
        if (n < 16)      v = B0S3Q * fc2_w2[k * 576 + 256 + (u - 16) * 16 + n];
      }
    } else {
      v = (n < 8) ? B0Q * fc2_w2[k * 576 + 512 + u * 8 + n] : 0.f;
    }
    dst[j] = f2bf(v);
  }
}

// A-fragment: 8 bf16 products x*h[k0+j], packed pairs
__device__ __forceinline__ short8 mk_afrag(float x, const float* hh) {
  union { short8 s8; __hip_bfloat162 h2[4]; } u;
  #pragma unroll
  for (int m = 0; m < 4; ++m)
    u.h2[m] = __float22bfloat162_rn(make_float2(x * hh[2 * m], x * hh[2 * m + 1]));
  return u.s8;
}

// ---------------------------------------------------------------------------
// CSR construction + deterministic gather (replaces 4M global atomics whose
// memory-side RMWs dominated r8: WRITE_SIZE 153MB vs ~21MB expected).
// ---------------------------------------------------------------------------
__global__ void hist_kernel(const int* __restrict__ edge_index,
                            int* __restrict__ counts) {
  int e = blockIdx.x * blockDim.x + threadIdx.x;
  if (e < NE) atomicAdd(&counts[edge_index[NE + e]], 1);
}

// single-block exclusive scan over counts[NN] -> offsets, tmpcur
__global__ void scan_kernel(const int* __restrict__ counts,
                            int* __restrict__ offsets,
                            int* __restrict__ tmpcur) {
  __shared__ int partial[256];
  int i = threadIdx.x;           // 256 threads x 40 elements
  int base = i * 40;
  int loc = 0;
  for (int j = 0; j < 40; ++j) {
    int idx = base + j;
    if (idx < NN) loc += counts[idx];
  }
  partial[i] = loc;
  __syncthreads();
  if (i == 0) {
    int run = 0;
    for (int k = 0; k < 256; ++k) { int t = partial[k]; partial[k] = run; run += t; }
  }
  __syncthreads();
  int acc = partial[i];
  for (int j = 0; j < 40; ++j) {
    int idx = base + j;
    if (idx < NN) {
      offsets[idx] = acc;
      tmpcur[idx] = acc;
      acc += counts[idx];
    }
  }
}

__global__ void fill_kernel(const int* __restrict__ edge_index,
                            int* __restrict__ tmpcur, int* __restrict__ list) {
  int e = blockIdx.x * blockDim.x + threadIdx.x;
  if (e >= NE) return;
  int d = edge_index[NE + e];
  int slot = atomicAdd(&tmpcur[d], 1);
  list[slot] = e;
}

// per-node insertion sort -> deterministic gather order
__global__ void sort_kernel(const int* __restrict__ offsets,
                            const int* __restrict__ counts,
                            int* __restrict__ list) {
  int n = blockIdx.x * blockDim.x + threadIdx.x;
  if (n >= NN) return;
  int b = offsets[n], c = counts[n];
  for (int i = 1; i < c; ++i) {
    int key = list[b + i];
    int j = i - 1;
    while (j >= 0 && list[b + j] > key) { list[b + j + 1] = list[b + j]; --j; }
    list[b + j + 1] = key;
  }
}

// thread = (node, channel): sorted sequential fmaf sum -> bit-deterministic
__global__ void gather_kernel(const float* __restrict__ he_new,
                              const float* __restrict__ norm,
                              const int* __restrict__ offsets,
                              const int* __restrict__ counts,
                              const int* __restrict__ list,
                              float* __restrict__ nf) {
  int t = blockIdx.x * blockDim.x + threadIdx.x;
  if (t >= NN * 40) return;
  int n = t / 40, ch = t - n * 40;
  int b = offsets[n], c = counts[n];
  float s = 0.f;
  for (int k = 0; k < c; ++k) {
    int e = list[b + k];
    s = fmaf(he_new[(size_t)e * 40 + ch], norm[e], s);
  }
  nf[t] = s;
}

// ---------------------------------------------------------------------------
// Edge kernel: identical to r8 except the atomic scatter tail is DELETED
// (pure he_new producer). 4 waves x 16 edges, de-aliased LDS slices.
// ---------------------------------------------------------------------------
#define XS1_OFF  0        // ushort [16][74]  (xs 48 | xvs 24, pad 2)
#define XV1_OFF  2368     // ushort [16][74]  ([i][24]: he8|src8|dst8)
#define H1_OFF   4736     // float  [16][17]
#define H2_OFF   5824     // float  [16][17]
#define SH_OFF   6912     // float  [16][4]
#define X2S_OFF  7168     // ushort [16][26]  (tmp_s 16 | tmpvs 8, pad 2)
#define X2V_OFF  8000     // ushort [16][26]  ([i][8])
#define OUT1_OFF 8832     // float  [16][57]  DEDICATED (no overlay)
#define OUT2_OFF 12480    // float  [16][49]  DEDICATED (no overlay)
#define SLICE    15616
#define SMEM_BYTES (4 * SLICE)

__global__ __launch_bounds__(256, 2) void edge_mfma_kernel(
    const float* __restrict__ hn, const float* __restrict__ he,
    const float* __restrict__ edge_vec, const float* __restrict__ emb,
    const float* __restrict__ fc1_w1, const float* __restrict__ fc2_w1,
    const int* __restrict__ edge_index, const unsigned short* __restrict__ wb,
    float* __restrict__ out_he) {
  __shared__ __align__(16) char smem[SMEM_BYTES];
  const int tid = threadIdx.x;
  const int wv = tid >> 6, l = tid & 63;
  char* sw = smem + wv * SLICE;              // this wave's slice
  unsigned short* XS1u = (unsigned short*)(sw + XS1_OFF);
  unsigned short* XV1u = (unsigned short*)(sw + XV1_OFF);
  float* H1f = (float*)(sw + H1_OFF);
  float* H2f = (float*)(sw + H2_OFF);
  float* SHf = (float*)(sw + SH_OFF);
  unsigned short* X2Su = (unsigned short*)(sw + X2S_OFF);
  unsigned short* X2Vu = (unsigned short*)(sw + X2V_OFF);
  float* OUT1f = (float*)(sw + OUT1_OFF);
  float* OUT2f = (float*)(sw + OUT2_OFF);

  const int e4 = l >> 2, part = l & 3;       // staging/epilogue mapping
  const int c = l & 15, grp = l >> 4;        // GEMM mapping
  const int k0 = (grp & 1) * 8;              // h-half for A-frag
  const int du = grp >> 1;                   // u parity offset
  const int e = blockIdx.x * 64 + wv * 16 + e4;
  const int eld = (e < NE) ? e : (NE - 1);   // clamped loads; stores predicated
  const short8* wbv = (const short8*)wb;

  // ---------- A: stage raw rows ----------
  {
    const float* her = he + (size_t)eld * 40;
    int srcn = edge_index[eld], dstn = edge_index[NE + eld];
    const float* hsr = hn + (size_t)srcn * 40;
    const float* hdr = hn + (size_t)dstn * 40;
    #pragma unroll
    for (int q = 0; q < 10; ++q) {
      int idx = part * 10 + q;
      float vee = her[idx], vs = hsr[idx], vd = hdr[idx];
      if (idx < 16) {
        XS1u[e4 * 74 + idx]      = f2bf(vee);
        XS1u[e4 * 74 + 16 + idx] = f2bf(vs);
        XS1u[e4 * 74 + 32 + idx] = f2bf(vd);
      } else {
        int m = idx - 16, up = m / 3, i = m % 3;
        XV1u[e4 * 74 + i * 24 + up]      = f2bf(vee);
        XV1u[e4 * 74 + i * 24 + 8 + up]  = f2bf(vs);
        XV1u[e4 * 74 + i * 24 + 16 + up] = f2bf(vd);
      }
    }
    if (part == 3) {
      float ev0 = edge_vec[eld * 3 + 0], ev1 = edge_vec[eld * 3 + 1],
            ev2 = edge_vec[eld * 3 + 2];
      float rn = rsqrtf(fmaf(ev0, ev0, fmaf(ev1, ev1, ev2 * ev2)));
      SHf[e4 * 4 + 0] = SQ3 * ev1 * rn;
      SHf[e4 * 4 + 1] = SQ3 * ev2 * rn;
      SHf[e4 * 4 + 2] = SQ3 * ev0 * rn;
    }
  }
  float em[10];
  #pragma unroll
  for (int m = 0; m < 10; ++m) em[m] = emb[(size_t)eld * 10 + m];
  __syncthreads();

  // ---------- C: derived (h1,h2 from em; xvs from XV1+SH) ----------
  {
    #pragma unroll
    for (int kk = 0; kk < 4; ++kk) {
      int k = part * 4 + kk;
      float s1 = 0.f, s2 = 0.f;
      #pragma unroll
      for (int m = 0; m < 10; ++m) {
        s1 = fmaf(em[m], fc1_w1[m * 16 + k], s1);
        s2 = fmaf(em[m], fc2_w1[m * 16 + k], s2);
      }
      H1f[e4 * 17 + k] = s1 > 0.f ? s1 * H_SCALE : 0.f;
      H2f[e4 * 17 + k] = s2 > 0.f ? s2 * H_SCALE : 0.f;
    }
    #pragma unroll
    for (int uu = 0; uu < 6; ++uu) {
      int us = part * 6 + uu;
      float a = 0.f;
      #pragma unroll
      for (int i = 0; i < 3; ++i)
        a = fmaf(bf2f(XV1u[e4 * 74 + i * 24 + us]), SHf[e4 * 4 + i], a);
      XS1u[e4 * 74 + 48 + us] = f2bf(a);
    }
  }
  __syncthreads();

  // ---------- E: layer-1 GEMMs (B from global) ----------
  float hh[8];
  #pragma unroll
  for (int j = 0; j < 8; ++j) hh[j] = H1f[c * 17 + k0 + j];

  f32x4 accA0 = {0.f, 0.f, 0.f, 0.f}, accA1 = {0.f, 0.f, 0.f, 0.f};
  #pragma unroll 6
  for (int s = 0; s < 36; ++s) {
    float x = bf2f(XS1u[c * 74 + 2 * s + du]);
    short8 a = mk_afrag(x, hh);
    short8 b0 = wbv[(size_t)(s * 2 + 0) * 64 + l];
    short8 b1 = wbv[(size_t)(s * 2 + 1) * 64 + l];
    accA0 = __builtin_amdgcn_mfma_f32_16x16x32_bf16(a, b0, accA0, 0, 0, 0);
    accA1 = __builtin_amdgcn_mfma_f32_16x16x32_bf16(a, b1, accA1, 0, 0, 0);
  }
  f32x4 accB0 = {0.f, 0.f, 0.f, 0.f}, accB1 = {0.f, 0.f, 0.f, 0.f},
        accB2 = {0.f, 0.f, 0.f, 0.f};
  #pragma unroll 4
  for (int s = 0; s < 12; ++s) {
    short8 b = wbv[(size_t)(72 + s) * 64 + l];
    float x0 = bf2f(XV1u[c * 74 + 0 * 24 + 2 * s + du]);
    float x1 = bf2f(XV1u[c * 74 + 1 * 24 + 2 * s + du]);
    float x2 = bf2f(XV1u[c * 74 + 2 * 24 + 2 * s + du]);
    accB0 = __builtin_amdgcn_mfma_f32_16x16x32_bf16(mk_afrag(x0, hh), b, accB0, 0, 0, 0);
    accB1 = __builtin_amdgcn_mfma_f32_16x16x32_bf16(mk_afrag(x1, hh), b, accB1, 0, 0, 0);
    accB2 = __builtin_amdgcn_mfma_f32_16x16x32_bf16(mk_afrag(x2, hh), b, accB2, 0, 0, 0);
  }
  __syncthreads();

  // ---------- F: flush layer-1 D-frags (D: col=l&15, row=(l>>4)*4+r) ----------
  #pragma unroll
  for (int r = 0; r < 4; ++r) {
    int eo = grp * 4 + r;
    OUT1f[eo * 57 + c]      = accA0[r];
    OUT1f[eo * 57 + 16 + c] = accA1[r];   // [16,24)=out_g, [24,32)=svw
    if (c < 8) {
      OUT1f[eo * 57 + 32 + c * 3 + 0] = accB0[r];
      OUT1f[eo * 57 + 32 + c * 3 + 1] = accB1[r];
      OUT1f[eo * 57 + 32 + c * 3 + 2] = accB2[r];
    }
  }
  __syncthreads();

  // ---------- G: nonlinearity -> layer-2 inputs ----------
  {
    #pragma unroll
    for (int j = 0; j < 4; ++j) {
      int wch = part * 4 + j;
      X2Su[e4 * 26 + wch] = f2bf(C_TANH * tanhf(OUT1f[e4 * 57 + wch]));
    }
    #pragma unroll
    for (int j = 0; j < 2; ++j) {
      int w = part * 2 + j;
      float g  = C_TANH * tanhf(OUT1f[e4 * 57 + 16 + w]);
      float sv = OUT1f[e4 * 57 + 24 + w];
      float tvs = 0.f;
      #pragma unroll
      for (int i = 0; i < 3; ++i) {
        float tv = g * fmaf(SHf[e4 * 4 + i], sv, OUT1f[e4 * 57 + 32 + w * 3 + i]);
        X2Vu[e4 * 26 + i * 8 + w] = f2bf(tv);
        tvs = fmaf(SHf[e4 * 4 + i], tv, tvs);
      }
      X2Su[e4 * 26 + 16 + w] = f2bf(tvs);
    }
  }
  __syncthreads();

  // ---------- H: layer-2 GEMMs ----------
  #pragma unroll
  for (int j = 0; j < 8; ++j) hh[j] = H2f[c * 17 + k0 + j];
  f32x4 accC0 = {0.f, 0.f, 0.f, 0.f}, accC1 = {0.f, 0.f, 0.f, 0.f};
  #pragma unroll 4
  for (int s = 0; s < 12; ++s) {
    float x = bf2f(X2Su[c * 26 + 2 * s + du]);
    short8 a = mk_afrag(x, hh);
    short8 b0 = wbv[(size_t)(84 + s * 2 + 0) * 64 + l];
    short8 b1 = wbv[(size_t)(84 + s * 2 + 1) * 64 + l];
    accC0 = __builtin_amdgcn_mfma_f32_16x16x32_bf16(a, b0, accC0, 0, 0, 0);
    accC1 = __builtin_amdgcn_mfma_f32_16x16x32_bf16(a, b1, accC1, 0, 0, 0);
  }
  f32x4 accD0 = {0.f, 0.f, 0.f, 0.f}, accD1 = {0.f, 0.f, 0.f, 0.f},
        accD2 = {0.f, 0.f, 0.f, 0.f};
  #pragma unroll
  for (int s = 0; s < 4; ++s) {
    short8 b = wbv[(size_t)(108 + s) * 64 + l];
    float x0 = bf2f(X2Vu[c * 26 + 0 * 8 + 2 * s + du]);
    float x1 = bf2f(X2Vu[c * 26 + 1 * 8 + 2 * s + du]);
    float x2 = bf2f(X2Vu[c * 26 + 2 * 8 + 2 * s + du]);
    accD0 = __builtin_amdgcn_mfma_f32_16x16x32_bf16(mk_afrag(x0, hh), b, accD0, 0, 0, 0);
    accD1 = __builtin_amdgcn_mfma_f32_16x16x32_bf16(mk_afrag(x1, hh), b, accD1, 0, 0, 0);
    accD2 = __builtin_amdgcn_mfma_f32_16x16x32_bf16(mk_afrag(x2, hh), b, accD2, 0, 0, 0);
  }
  __syncthreads();

  // ---------- I: flush layer-2 ----------
  #pragma unroll
  for (int r = 0; r < 4; ++r) {
    int eo = grp * 4 + r;
    OUT2f[eo * 49 + c] = accC0[r];
    if (c < 8) {
      OUT2f[eo * 49 + 16 + c] = accC1[r];
      OUT2f[eo * 49 + 24 + c * 3 + 0] = accD0[r];
      OUT2f[eo * 49 + 24 + c * 3 + 1] = accD1[r];
      OUT2f[eo * 49 + 24 + c * 3 + 2] = accD2[r];
    }
  }
  __syncthreads();

  // ---------- J: epilogue (plain stores only; scatter moved to gather) -----
  if (e < NE) {
    const float* her = he + (size_t)e * 40;
    float* o = out_he + (size_t)e * 40;
    #pragma unroll
    for (int q = 0; q < 10; ++q) {
      int j = part * 10 + q;
      float val;
      if (j < 16) {
        val = her[j] + OUT2f[e4 * 49 + j];
      } else {
        int m = j - 16, w = m / 3, i = m % 3;
        val = her[j] + fmaf(SHf[e4 * 4 + i], OUT2f[e4 * 49 + 16 + w],
                            OUT2f[e4 * 49 + 24 + w * 3 + i]);
      }
      o[j] = val;
    }
  }
}

// ---------------------------------------------------------------------------
// Node kernel: one thread per node (r8 structure), nf now plain f32.
// ---------------------------------------------------------------------------
__global__ __launch_bounds__(256) void node_kernel(
    const float* __restrict__ hn, const float* __restrict__ nf,
    const float* __restrict__ wl1_s, const float* __restrict__ wl1_g,
    const float* __restrict__ wl1_v, const float* __restrict__ wl2_s,
    const float* __restrict__ wl2_v, float* __restrict__ out) {
  int n = blockIdx.x * blockDim.x + threadIdx.x;
  if (n >= NN) return;
  const float* rh = hn + (size_t)n * 40;
  const float* rf = nf + (size_t)n * 40;

  float cs[32], cv[16][3];
  #pragma unroll
  for (int u = 0; u < 16; ++u) cs[u] = rh[u];
  #pragma unroll
  for (int u = 0; u < 16; ++u) cs[16 + u] = rf[u];
  #pragma unroll
  for (int u = 0; u < 8; ++u) {
    cv[u][0] = rh[16 + u * 3 + 0];
    cv[u][1] = rh[16 + u * 3 + 1];
    cv[u][2] = rh[16 + u * 3 + 2];
    cv[8 + u][0] = rf[16 + u * 3 + 0];
    cv[8 + u][1] = rf[16 + u * 3 + 1];
    cv[8 + u][2] = rf[16 + u * 3 + 2];
  }

  float l1s[16], l1g[8], l1v[8][3];
  #pragma unroll
  for (int w = 0; w < 16; ++w) l1s[w] = 0.f;
  #pragma unroll
  for (int w = 0; w < 8; ++w) {
    l1g[w] = 0.f; l1v[w][0] = 0.f; l1v[w][1] = 0.f; l1v[w][2] = 0.f;
  }
  #pragma unroll
  for (int u = 0; u < 32; ++u) {
    float x = cs[u];
    #pragma unroll
    for (int w = 0; w < 16; ++w) l1s[w] = fmaf(x, wl1_s[u * 16 + w], l1s[w]);
    #pragma unroll
    for (int w = 0; w < 8; ++w) l1g[w] = fmaf(x, wl1_g[u * 8 + w], l1g[w]);
  }
  #pragma unroll
  for (int u = 0; u < 16; ++u) {
    #pragma unroll
    for (int w = 0; w < 8; ++w) {
      float wv = wl1_v[u * 8 + w];
      l1v[w][0] = fmaf(cv[u][0], wv, l1v[w][0]);
      l1v[w][1] = fmaf(cv[u][1], wv, l1v[w][1]);
      l1v[w][2] = fmaf(cv[u][2], wv, l1v[w][2]);
    }
  }

  float gs[16], gv[8][3];
  #pragma unroll
  for (int w = 0; w < 16; ++w) gs[w] = C_TANH * tanhf(l1s[w] * S32);
  #pragma unroll
  for (int w = 0; w < 8; ++w) {
    float g = C_TANH * tanhf(l1g[w] * S32);
    gv[w][0] = g * l1v[w][0] * S16;
    gv[w][1] = g * l1v[w][1] * S16;
    gv[w][2] = g * l1v[w][2] * S16;
  }

  float l2s[16], l2v[8][3];
  #pragma unroll
  for (int v = 0; v < 16; ++v) l2s[v] = 0.f;
  #pragma unroll
  for (int v = 0; v < 8; ++v) { l2v[v][0] = 0.f; l2v[v][1] = 0.f; l2v[v][2] = 0.f; }
  #pragma unroll
  for (int w = 0; w < 16; ++w) {
    float g = gs[w];
    #pragma unroll
    for (int v = 0; v < 16; ++v) l2s[v] = fmaf(g, wl2_s[w * 16 + v], l2s[v]);
  }
  #pragma unroll
  for (int w = 0; w < 8; ++w) {
    #pragma unroll
    for (int v = 0; v < 8; ++v) {
      float wv = wl2_v[w * 8 + v];
      l2v[v][0] = fmaf(gv[w][0], wv, l2v[v][0]);
      l2v[v][1] = fmaf(gv[w][1], wv, l2v[v][1]);
      l2v[v][2] = fmaf(gv[w][2], wv, l2v[v][2]);
    }
  }

  float* o = out + (size_t)n * 40;
  #pragma unroll
  for (int v = 0; v < 16; ++v) o[v] = rh[v] + l2s[v] * S16;
  #pragma unroll
  for (int v = 0; v < 8; ++v) {
    o[16 + v * 3 + 0] = rh[16 + v * 3 + 0] + l2v[v][0] * S8;
    o[16 + v * 3 + 1] = rh[16 + v * 3 + 1] + l2v[v][1] * S8;
    o[16 + v * 3 + 2] = rh[16 + v * 3 + 2] + l2v[v][2] * S8;
  }
}

extern "C" void kernel_launch(void* const* d_in, const int* in_sizes, int n_in,
                              void* d_out, int out_size, void* d_ws,
                              size_t ws_size, hipStream_t stream) {
  const float* hn       = (const float*)d_in[0];
  const float* he       = (const float*)d_in[1];
  const float* edge_vec = (const float*)d_in[2];
  const float* emb      = (const float*)d_in[3];
  const float* norm     = (const float*)d_in[4];
  const float* fc1_w1   = (const float*)d_in[5];
  const float* fc1_w2   = (const float*)d_in[6];
  const float* fc2_w1   = (const float*)d_in[7];
  const float* fc2_w2   = (const float*)d_in[8];
  const float* wl1_s    = (const float*)d_in[9];
  const float* wl1_g    = (const float*)d_in[10];
  const float* wl1_v    = (const float*)d_in[11];
  const float* wl2_s    = (const float*)d_in[12];
  const float* wl2_v    = (const float*)d_in[13];
  const int*   edge_index = (const int*)d_in[14];

  char* ws = (char*)d_ws;
  unsigned short* wb = (unsigned short*)ws;          // [0, 114688) blobs
  int* counts  = (int*)(ws + 131072);                // 10K int
  int* offsets = (int*)(ws + 171072);                // 10K int
  int* tmpcur  = (int*)(ws + 211072);                // 10K int
  int* list    = (int*)(ws + 251072);                // 100K int
  float* nf    = (float*)(ws + 651072);              // NN*40 f32 (1.6MB)

  hipMemsetAsync(counts, 0, NN * sizeof(int), stream);
  prep2_kernel<<<dim3((112 * 64 + 255) / 256), dim3(256), 0, stream>>>(
      fc1_w2, fc2_w2, wb);
  hist_kernel<<<dim3((NE + 255) / 256), dim3(256), 0, stream>>>(edge_index,
                                                                counts);
  scan_kernel<<<dim3(1), dim3(256), 0, stream>>>(counts, offsets, tmpcur);
  fill_kernel<<<dim3((NE + 255) / 256), dim3(256), 0, stream>>>(edge_index,
                                                                tmpcur, list);
  sort_kernel<<<dim3((NN + 255) / 256), dim3(256), 0, stream>>>(offsets,
                                                                counts, list);
  float* out = (float*)d_out;
  float* out_he = out + (size_t)NN * 40;
  edge_mfma_kernel<<<dim3(NBLK2), dim3(256), 0, stream>>>(
      hn, he, edge_vec, emb, fc1_w1, fc2_w1, edge_index, wb, out_he);
  gather_kernel<<<dim3((NN * 40 + 255) / 256), dim3(256), 0, stream>>>(
      out_he, norm, offsets, counts, list, nf);
  node_kernel<<<dim3((NN + 255) / 256), dim3(256), 0, stream>>>(
      hn, nf, wl1_s, wl1_g, wl1_v, wl2_s, wl2_v, out);
}

// Round 10
// 195.852 us; speedup vs baseline: 1.1802x; 1.1802x over previous
//
#include <hip/hip_runtime.h>
#include <hip/hip_bf16.h>
#include <math.h>

#define NN 10000
#define NE 100000
#define NBLK2 ((NE + 63) / 64)   // 1563 blocks, 64 edges (4 waves x 16)

typedef __attribute__((ext_vector_type(4))) float f32x4;
typedef __attribute__((ext_vector_type(8))) short short8;

static constexpr float C_TANH  = 1.5927f;
static constexpr float SQ3     = 1.7320508075688772f;
static constexpr float H_SCALE = 0.4472135954999579f;   // C_RELU/sqrt(10)
// output-region scales with 1/sqrt(16) folded in
static constexpr float A0Q   = 0.11785113019775793f * 0.25f;  // sqrt(1/72)/4
static constexpr float A0S3Q = 0.06804138174397717f * 0.25f;  // sqrt(1/216)/4
static constexpr float B0Q   = 0.20412414523193154f * 0.25f;  // sqrt(1/24)/4
static constexpr float B0S3Q = 0.11785113019775793f * 0.25f;  // sqrt(1/72)/4
static constexpr float S32 = 0.1767766952966369f;
static constexpr float S16 = 0.25f;
static constexpr float S8  = 0.3535533905932738f;

__device__ __forceinline__ unsigned short f2bf(float f) {
  union { float f; unsigned u; } cv; cv.f = f;
  unsigned r = cv.u + 0x7fffu + ((cv.u >> 16) & 1u);
  return (unsigned short)(r >> 16);
}
__device__ __forceinline__ float bf2f(unsigned short s) {
  return __uint_as_float(((unsigned)s) << 16);
}

// ---------------------------------------------------------------------------
// Prep: 4 frag-linear bf16 weight blobs (112KB) in d_ws (unchanged since r3).
// ---------------------------------------------------------------------------
__global__ void prep2_kernel(const float* __restrict__ fc1_w2,
                             const float* __restrict__ fc2_w2,
                             unsigned short* __restrict__ wb) {
  int t = blockIdx.x * blockDim.x + threadIdx.x;
  if (t >= 112 * 64) return;
  int lane = t & 63, blk = t >> 6;
  int grp = lane >> 4, c = lane & 15;
  unsigned short* dst = wb + (size_t)blk * 512 + lane * 8;
  int gemm, s, nt;
  if (blk < 72)       { gemm = 0; s = blk >> 1;        nt = blk & 1; }
  else if (blk < 84)  { gemm = 1; s = blk - 72;        nt = 0; }
  else if (blk < 108) { gemm = 2; s = (blk - 84) >> 1; nt = (blk - 84) & 1; }
  else                { gemm = 3; s = blk - 108;       nt = 0; }
  int n = nt * 16 + c;
  #pragma unroll
  for (int j = 0; j < 8; ++j) {
    int K = 32 * s + grp * 8 + j;
    int u = K >> 4, k = K & 15;
    float v = 0.f;
    if (gemm == 0) {
      if (n < 16) v = (u < 48) ? A0Q   * fc1_w2[k * 2304 + u * 16 + n]
                               : A0S3Q * fc1_w2[k * 2304 + 1152 + (u - 48) * 16 + n];
      else if (n < 24) { int w = n - 16;
        v = (u < 48) ? A0Q   * fc1_w2[k * 2304 + 768 + u * 8 + w]
                     : A0S3Q * fc1_w2[k * 2304 + 1536 + (u - 48) * 8 + w];
      } else { int w = n - 24;
        v = (u < 48) ? A0Q * fc1_w2[k * 2304 + 1728 + u * 8 + w] : 0.f;
      }
    } else if (gemm == 1) {
      v = (n < 8) ? A0Q * fc1_w2[k * 2304 + 2112 + u * 8 + n] : 0.f;
    } else if (gemm == 2) {
      if (u < 16) {
        if (n < 16)      v = B0Q * fc2_w2[k * 576 + u * 16 + n];
        else if (n < 24) v = B0Q * fc2_w2[k * 576 + 384 + u * 8 + (n - 16)];
      } else {
        if (n < 16)      v = B0S3Q * fc2_w2[k * 576 + 256 + (u - 16) * 16 + n];
      }
    } else {
      v = (n < 8) ? B0Q * fc2_w2[k * 576 + 512 + u * 8 + n] : 0.f;
    }
    dst[j] = f2bf(v);
  }
}

// A-fragment: 8 bf16 products x*h[k0+j], packed pairs
__device__ __forceinline__ short8 mk_afrag(float x, const float* hh) {
  union { short8 s8; __hip_bfloat162 h2[4]; } u;
  #pragma unroll
  for (int m = 0; m < 4; ++m)
    u.h2[m] = __float22bfloat162_rn(make_float2(x * hh[2 * m], x * hh[2 * m + 1]));
  return u.s8;
}

// ---------------------------------------------------------------------------
// CSR construction (NO per-node sort: the gather accumulates in s64
// fixed-point, which is order-independent, so list order need not be
// deterministic). sort_kernel was ~80µs of latency-bound serial work.
// ---------------------------------------------------------------------------
__global__ void hist_kernel(const int* __restrict__ edge_index,
                            int* __restrict__ counts) {
  int e = blockIdx.x * blockDim.x + threadIdx.x;
  if (e < NE) atomicAdd(&counts[edge_index[NE + e]], 1);
}

// single-block exclusive scan over counts[NN] -> offsets, tmpcur
__global__ void scan_kernel(const int* __restrict__ counts,
                            int* __restrict__ offsets,
                            int* __restrict__ tmpcur) {
  __shared__ int partial[256];
  int i = threadIdx.x;           // 256 threads x 40 elements
  int base = i * 40;
  int loc = 0;
  for (int j = 0; j < 40; ++j) {
    int idx = base + j;
    if (idx < NN) loc += counts[idx];
  }
  partial[i] = loc;
  __syncthreads();
  if (i == 0) {
    int run = 0;
    for (int k = 0; k < 256; ++k) { int t = partial[k]; partial[k] = run; run += t; }
  }
  __syncthreads();
  int acc = partial[i];
  for (int j = 0; j < 40; ++j) {
    int idx = base + j;
    if (idx < NN) {
      offsets[idx] = acc;
      tmpcur[idx] = acc;
      acc += counts[idx];
    }
  }
}

__global__ void fill_kernel(const int* __restrict__ edge_index,
                            int* __restrict__ tmpcur, int* __restrict__ list) {
  int e = blockIdx.x * blockDim.x + threadIdx.x;
  if (e >= NE) return;
  int d = edge_index[NE + e];
  int slot = atomicAdd(&tmpcur[d], 1);
  list[slot] = e;
}

// thread = (node, channel): s64 fixed-point sum (scale 2^32) -> result is
// independent of list order -> bit-deterministic across replays.
__global__ void gather_kernel(const float* __restrict__ he_new,
                              const float* __restrict__ norm,
                              const int* __restrict__ offsets,
                              const int* __restrict__ counts,
                              const int* __restrict__ list,
                              float* __restrict__ nf) {
  int t = blockIdx.x * blockDim.x + threadIdx.x;
  if (t >= NN * 40) return;
  int n = t / 40, ch = t - n * 40;
  int b = offsets[n], c = counts[n];
  long long acc = 0;
  for (int k = 0; k < c; ++k) {
    int e = list[b + k];
    double p = (double)he_new[(size_t)e * 40 + ch] * (double)norm[e];
    acc += (long long)llrint(p * 4294967296.0);
  }
  nf[t] = (float)((double)acc * 2.3283064365386963e-10);
}

// ---------------------------------------------------------------------------
// Edge kernel: unchanged from r9 (85µs, verified). 4 waves x 16 edges,
// de-aliased LDS slices, B-operands streamed from L2-resident global blob.
// ---------------------------------------------------------------------------
#define XS1_OFF  0        // ushort [16][74]  (xs 48 | xvs 24, pad 2)
#define XV1_OFF  2368     // ushort [16][74]  ([i][24]: he8|src8|dst8)
#define H1_OFF   4736     // float  [16][17]
#define H2_OFF   5824     // float  [16][17]
#define SH_OFF   6912     // float  [16][4]
#define X2S_OFF  7168     // ushort [16][26]  (tmp_s 16 | tmpvs 8, pad 2)
#define X2V_OFF  8000     // ushort [16][26]  ([i][8])
#define OUT1_OFF 8832     // float  [16][57]  DEDICATED (no overlay)
#define OUT2_OFF 12480    // float  [16][49]  DEDICATED (no overlay)
#define SLICE    15616
#define SMEM_BYTES (4 * SLICE)

__global__ __launch_bounds__(256, 2) void edge_mfma_kernel(
    const float* __restrict__ hn, const float* __restrict__ he,
    const float* __restrict__ edge_vec, const float* __restrict__ emb,
    const float* __restrict__ fc1_w1, const float* __restrict__ fc2_w1,
    const int* __restrict__ edge_index, const unsigned short* __restrict__ wb,
    float* __restrict__ out_he) {
  __shared__ __align__(16) char smem[SMEM_BYTES];
  const int tid = threadIdx.x;
  const int wv = tid >> 6, l = tid & 63;
  char* sw = smem + wv * SLICE;              // this wave's slice
  unsigned short* XS1u = (unsigned short*)(sw + XS1_OFF);
  unsigned short* XV1u = (unsigned short*)(sw + XV1_OFF);
  float* H1f = (float*)(sw + H1_OFF);
  float* H2f = (float*)(sw + H2_OFF);
  float* SHf = (float*)(sw + SH_OFF);
  unsigned short* X2Su = (unsigned short*)(sw + X2S_OFF);
  unsigned short* X2Vu = (unsigned short*)(sw + X2V_OFF);
  float* OUT1f = (float*)(sw + OUT1_OFF);
  float* OUT2f = (float*)(sw + OUT2_OFF);

  const int e4 = l >> 2, part = l & 3;       // staging/epilogue mapping
  const int c = l & 15, grp = l >> 4;        // GEMM mapping
  const int k0 = (grp & 1) * 8;              // h-half for A-frag
  const int du = grp >> 1;                   // u parity offset
  const int e = blockIdx.x * 64 + wv * 16 + e4;
  const int eld = (e < NE) ? e : (NE - 1);   // clamped loads; stores predicated
  const short8* wbv = (const short8*)wb;

  // ---------- A: stage raw rows ----------
  {
    const float* her = he + (size_t)eld * 40;
    int srcn = edge_index[eld], dstn = edge_index[NE + eld];
    const float* hsr = hn + (size_t)srcn * 40;
    const float* hdr = hn + (size_t)dstn * 40;
    #pragma unroll
    for (int q = 0; q < 10; ++q) {
      int idx = part * 10 + q;
      float vee = her[idx], vs = hsr[idx], vd = hdr[idx];
      if (idx < 16) {
        XS1u[e4 * 74 + idx]      = f2bf(vee);
        XS1u[e4 * 74 + 16 + idx] = f2bf(vs);
        XS1u[e4 * 74 + 32 + idx] = f2bf(vd);
      } else {
        int m = idx - 16, up = m / 3, i = m % 3;
        XV1u[e4 * 74 + i * 24 + up]      = f2bf(vee);
        XV1u[e4 * 74 + i * 24 + 8 + up]  = f2bf(vs);
        XV1u[e4 * 74 + i * 24 + 16 + up] = f2bf(vd);
      }
    }
    if (part == 3) {
      float ev0 = edge_vec[eld * 3 + 0], ev1 = edge_vec[eld * 3 + 1],
            ev2 = edge_vec[eld * 3 + 2];
      float rn = rsqrtf(fmaf(ev0, ev0, fmaf(ev1, ev1, ev2 * ev2)));
      SHf[e4 * 4 + 0] = SQ3 * ev1 * rn;
      SHf[e4 * 4 + 1] = SQ3 * ev2 * rn;
      SHf[e4 * 4 + 2] = SQ3 * ev0 * rn;
    }
  }
  float em[10];
  #pragma unroll
  for (int m = 0; m < 10; ++m) em[m] = emb[(size_t)eld * 10 + m];
  __syncthreads();

  // ---------- C: derived (h1,h2 from em; xvs from XV1+SH) ----------
  {
    #pragma unroll
    for (int kk = 0; kk < 4; ++kk) {
      int k = part * 4 + kk;
      float s1 = 0.f, s2 = 0.f;
      #pragma unroll
      for (int m = 0; m < 10; ++m) {
        s1 = fmaf(em[m], fc1_w1[m * 16 + k], s1);
        s2 = fmaf(em[m], fc2_w1[m * 16 + k], s2);
      }
      H1f[e4 * 17 + k] = s1 > 0.f ? s1 * H_SCALE : 0.f;
      H2f[e4 * 17 + k] = s2 > 0.f ? s2 * H_SCALE : 0.f;
    }
    #pragma unroll
    for (int uu = 0; uu < 6; ++uu) {
      int us = part * 6 + uu;
      float a = 0.f;
      #pragma unroll
      for (int i = 0; i < 3; ++i)
        a = fmaf(bf2f(XV1u[e4 * 74 + i * 24 + us]), SHf[e4 * 4 + i], a);
      XS1u[e4 * 74 + 48 + us] = f2bf(a);
    }
  }
  __syncthreads();

  // ---------- E: layer-1 GEMMs (B from global) ----------
  float hh[8];
  #pragma unroll
  for (int j = 0; j < 8; ++j) hh[j] = H1f[c * 17 + k0 + j];

  f32x4 accA0 = {0.f, 0.f, 0.f, 0.f}, accA1 = {0.f, 0.f, 0.f, 0.f};
  #pragma unroll 6
  for (int s = 0; s < 36; ++s) {
    float x = bf2f(XS1u[c * 74 + 2 * s + du]);
    short8 a = mk_afrag(x, hh);
    short8 b0 = wbv[(size_t)(s * 2 + 0) * 64 + l];
    short8 b1 = wbv[(size_t)(s * 2 + 1) * 64 + l];
    accA0 = __builtin_amdgcn_mfma_f32_16x16x32_bf16(a, b0, accA0, 0, 0, 0);
    accA1 = __builtin_amdgcn_mfma_f32_16x16x32_bf16(a, b1, accA1, 0, 0, 0);
  }
  f32x4 accB0 = {0.f, 0.f, 0.f, 0.f}, accB1 = {0.f, 0.f, 0.f, 0.f},
        accB2 = {0.f, 0.f, 0.f, 0.f};
  #pragma unroll 4
  for (int s = 0; s < 12; ++s) {
    short8 b = wbv[(size_t)(72 + s) * 64 + l];
    float x0 = bf2f(XV1u[c * 74 + 0 * 24 + 2 * s + du]);
    float x1 = bf2f(XV1u[c * 74 + 1 * 24 + 2 * s + du]);
    float x2 = bf2f(XV1u[c * 74 + 2 * 24 + 2 * s + du]);
    accB0 = __builtin_amdgcn_mfma_f32_16x16x32_bf16(mk_afrag(x0, hh), b, accB0, 0, 0, 0);
    accB1 = __builtin_amdgcn_mfma_f32_16x16x32_bf16(mk_afrag(x1, hh), b, accB1, 0, 0, 0);
    accB2 = __builtin_amdgcn_mfma_f32_16x16x32_bf16(mk_afrag(x2, hh), b, accB2, 0, 0, 0);
  }
  __syncthreads();

  // ---------- F: flush layer-1 D-frags (D: col=l&15, row=(l>>4)*4+r) ----------
  #pragma unroll
  for (int r = 0; r < 4; ++r) {
    int eo = grp * 4 + r;
    OUT1f[eo * 57 + c]      = accA0[r];
    OUT1f[eo * 57 + 16 + c] = accA1[r];   // [16,24)=out_g, [24,32)=svw
    if (c < 8) {
      OUT1f[eo * 57 + 32 + c * 3 + 0] = accB0[r];
      OUT1f[eo * 57 + 32 + c * 3 + 1] = accB1[r];
      OUT1f[eo * 57 + 32 + c * 3 + 2] = accB2[r];
    }
  }
  __syncthreads();

  // ---------- G: nonlinearity -> layer-2 inputs ----------
  {
    #pragma unroll
    for (int j = 0; j < 4; ++j) {
      int wch = part * 4 + j;
      X2Su[e4 * 26 + wch] = f2bf(C_TANH * tanhf(OUT1f[e4 * 57 + wch]));
    }
    #pragma unroll
    for (int j = 0; j < 2; ++j) {
      int w = part * 2 + j;
      float g  = C_TANH * tanhf(OUT1f[e4 * 57 + 16 + w]);
      float sv = OUT1f[e4 * 57 + 24 + w];
      float tvs = 0.f;
      #pragma unroll
      for (int i = 0; i < 3; ++i) {
        float tv = g * fmaf(SHf[e4 * 4 + i], sv, OUT1f[e4 * 57 + 32 + w * 3 + i]);
        X2Vu[e4 * 26 + i * 8 + w] = f2bf(tv);
        tvs = fmaf(SHf[e4 * 4 + i], tv, tvs);
      }
      X2Su[e4 * 26 + 16 + w] = f2bf(tvs);
    }
  }
  __syncthreads();

  // ---------- H: layer-2 GEMMs ----------
  #pragma unroll
  for (int j = 0; j < 8; ++j) hh[j] = H2f[c * 17 + k0 + j];
  f32x4 accC0 = {0.f, 0.f, 0.f, 0.f}, accC1 = {0.f, 0.f, 0.f, 0.f};
  #pragma unroll 4
  for (int s = 0; s < 12; ++s) {
    float x = bf2f(X2Su[c * 26 + 2 * s + du]);
    short8 a = mk_afrag(x, hh);
    short8 b0 = wbv[(size_t)(84 + s * 2 + 0) * 64 + l];
    short8 b1 = wbv[(size_t)(84 + s * 2 + 1) * 64 + l];
    accC0 = __builtin_amdgcn_mfma_f32_16x16x32_bf16(a, b0, accC0, 0, 0, 0);
    accC1 = __builtin_amdgcn_mfma_f32_16x16x32_bf16(a, b1, accC1, 0, 0, 0);
  }
  f32x4 accD0 = {0.f, 0.f, 0.f, 0.f}, accD1 = {0.f, 0.f, 0.f, 0.f},
        accD2 = {0.f, 0.f, 0.f, 0.f};
  #pragma unroll
  for (int s = 0; s < 4; ++s) {
    short8 b = wbv[(size_t)(108 + s) * 64 + l];
    float x0 = bf2f(X2Vu[c * 26 + 0 * 8 + 2 * s + du]);
    float x1 = bf2f(X2Vu[c * 26 + 1 * 8 + 2 * s + du]);
    float x2 = bf2f(X2Vu[c * 26 + 2 * 8 + 2 * s + du]);
    accD0 = __builtin_amdgcn_mfma_f32_16x16x32_bf16(mk_afrag(x0, hh), b, accD0, 0, 0, 0);
    accD1 = __builtin_amdgcn_mfma_f32_16x16x32_bf16(mk_afrag(x1, hh), b, accD1, 0, 0, 0);
    accD2 = __builtin_amdgcn_mfma_f32_16x16x32_bf16(mk_afrag(x2, hh), b, accD2, 0, 0, 0);
  }
  __syncthreads();

  // ---------- I: flush layer-2 ----------
  #pragma unroll
  for (int r = 0; r < 4; ++r) {
    int eo = grp * 4 + r;
    OUT2f[eo * 49 + c] = accC0[r];
    if (c < 8) {
      OUT2f[eo * 49 + 16 + c] = accC1[r];
      OUT2f[eo * 49 + 24 + c * 3 + 0] = accD0[r];
      OUT2f[eo * 49 + 24 + c * 3 + 1] = accD1[r];
      OUT2f[eo * 49 + 24 + c * 3 + 2] = accD2[r];
    }
  }
  __syncthreads();

  // ---------- J: epilogue (plain stores; gather handles the segment-sum) ----
  if (e < NE) {
    const float* her = he + (size_t)e * 40;
    float* o = out_he + (size_t)e * 40;
    #pragma unroll
    for (int q = 0; q < 10; ++q) {
      int j = part * 10 + q;
      float val;
      if (j < 16) {
        val = her[j] + OUT2f[e4 * 49 + j];
      } else {
        int m = j - 16, w = m / 3, i = m % 3;
        val = her[j] + fmaf(SHf[e4 * 4 + i], OUT2f[e4 * 49 + 16 + w],
                            OUT2f[e4 * 49 + 24 + w * 3 + i]);
      }
      o[j] = val;
    }
  }
}

// ---------------------------------------------------------------------------
// Node kernel: one thread per node (unchanged from r9).
// ---------------------------------------------------------------------------
__global__ __launch_bounds__(256) void node_kernel(
    const float* __restrict__ hn, const float* __restrict__ nf,
    const float* __restrict__ wl1_s, const float* __restrict__ wl1_g,
    const float* __restrict__ wl1_v, const float* __restrict__ wl2_s,
    const float* __restrict__ wl2_v, float* __restrict__ out) {
  int n = blockIdx.x * blockDim.x + threadIdx.x;
  if (n >= NN) return;
  const float* rh = hn + (size_t)n * 40;
  const float* rf = nf + (size_t)n * 40;

  float cs[32], cv[16][3];
  #pragma unroll
  for (int u = 0; u < 16; ++u) cs[u] = rh[u];
  #pragma unroll
  for (int u = 0; u < 16; ++u) cs[16 + u] = rf[u];
  #pragma unroll
  for (int u = 0; u < 8; ++u) {
    cv[u][0] = rh[16 + u * 3 + 0];
    cv[u][1] = rh[16 + u * 3 + 1];
    cv[u][2] = rh[16 + u * 3 + 2];
    cv[8 + u][0] = rf[16 + u * 3 + 0];
    cv[8 + u][1] = rf[16 + u * 3 + 1];
    cv[8 + u][2] = rf[16 + u * 3 + 2];
  }

  float l1s[16], l1g[8], l1v[8][3];
  #pragma unroll
  for (int w = 0; w < 16; ++w) l1s[w] = 0.f;
  #pragma unroll
  for (int w = 0; w < 8; ++w) {
    l1g[w] = 0.f; l1v[w][0] = 0.f; l1v[w][1] = 0.f; l1v[w][2] = 0.f;
  }
  #pragma unroll
  for (int u = 0; u < 32; ++u) {
    float x = cs[u];
    #pragma unroll
    for (int w = 0; w < 16; ++w) l1s[w] = fmaf(x, wl1_s[u * 16 + w], l1s[w]);
    #pragma unroll
    for (int w = 0; w < 8; ++w) l1g[w] = fmaf(x, wl1_g[u * 8 + w], l1g[w]);
  }
  #pragma unroll
  for (int u = 0; u < 16; ++u) {
    #pragma unroll
    for (int w = 0; w < 8; ++w) {
      float wv = wl1_v[u * 8 + w];
      l1v[w][0] = fmaf(cv[u][0], wv, l1v[w][0]);
      l1v[w][1] = fmaf(cv[u][1], wv, l1v[w][1]);
      l1v[w][2] = fmaf(cv[u][2], wv, l1v[w][2]);
    }
  }

  float gs[16], gv[8][3];
  #pragma unroll
  for (int w = 0; w < 16; ++w) gs[w] = C_TANH * tanhf(l1s[w] * S32);
  #pragma unroll
  for (int w = 0; w < 8; ++w) {
    float g = C_TANH * tanhf(l1g[w] * S32);
    gv[w][0] = g * l1v[w][0] * S16;
    gv[w][1] = g * l1v[w][1] * S16;
    gv[w][2] = g * l1v[w][2] * S16;
  }

  float l2s[16], l2v[8][3];
  #pragma unroll
  for (int v = 0; v < 16; ++v) l2s[v] = 0.f;
  #pragma unroll
  for (int v = 0; v < 8; ++v) { l2v[v][0] = 0.f; l2v[v][1] = 0.f; l2v[v][2] = 0.f; }
  #pragma unroll
  for (int w = 0; w < 16; ++w) {
    float g = gs[w];
    #pragma unroll
    for (int v = 0; v < 16; ++v) l2s[v] = fmaf(g, wl2_s[w * 16 + v], l2s[v]);
  }
  #pragma unroll
  for (int w = 0; w < 8; ++w) {
    #pragma unroll
    for (int v = 0; v < 8; ++v) {
      float wv = wl2_v[w * 8 + v];
      l2v[v][0] = fmaf(gv[w][0], wv, l2v[v][0]);
      l2v[v][1] = fmaf(gv[w][1], wv, l2v[v][1]);
      l2v[v][2] = fmaf(gv[w][2], wv, l2v[v][2]);
    }
  }

  float* o = out + (size_t)n * 40;
  #pragma unroll
  for (int v = 0; v < 16; ++v) o[v] = rh[v] + l2s[v] * S16;
  #pragma unroll
  for (int v = 0; v < 8; ++v) {
    o[16 + v * 3 + 0] = rh[16 + v * 3 + 0] + l2v[v][0] * S8;
    o[16 + v * 3 + 1] = rh[16 + v * 3 + 1] + l2v[v][1] * S8;
    o[16 + v * 3 + 2] = rh[16 + v * 3 + 2] + l2v[v][2] * S8;
  }
}

extern "C" void kernel_launch(void* const* d_in, const int* in_sizes, int n_in,
                              void* d_out, int out_size, void* d_ws,
                              size_t ws_size, hipStream_t stream) {
  const float* hn       = (const float*)d_in[0];
  const float* he       = (const float*)d_in[1];
  const float* edge_vec = (const float*)d_in[2];
  const float* emb      = (const float*)d_in[3];
  const float* norm     = (const float*)d_in[4];
  const float* fc1_w1   = (const float*)d_in[5];
  const float* fc1_w2   = (const float*)d_in[6];
  const float* fc2_w1   = (const float*)d_in[7];
  const float* fc2_w2   = (const float*)d_in[8];
  const float* wl1_s    = (const float*)d_in[9];
  const float* wl1_g    = (const float*)d_in[10];
  const float* wl1_v    = (const float*)d_in[11];
  const float* wl2_s    = (const float*)d_in[12];
  const float* wl2_v    = (const float*)d_in[13];
  const int*   edge_index = (const int*)d_in[14];

  char* ws = (char*)d_ws;
  unsigned short* wb = (unsigned short*)ws;          // [0, 114688) blobs
  int* counts  = (int*)(ws + 131072);                // 10K int
  int* offsets = (int*)(ws + 171072);                // 10K int
  int* tmpcur  = (int*)(ws + 211072);                // 10K int
  int* list    = (int*)(ws + 251072);                // 100K int
  float* nf    = (float*)(ws + 651072);              // NN*40 f32 (1.6MB)

  hipMemsetAsync(counts, 0, NN * sizeof(int), stream);
  prep2_kernel<<<dim3((112 * 64 + 255) / 256), dim3(256), 0, stream>>>(
      fc1_w2, fc2_w2, wb);
  hist_kernel<<<dim3((NE + 255) / 256), dim3(256), 0, stream>>>(edge_index,
                                                                counts);
  scan_kernel<<<dim3(1), dim3(256), 0, stream>>>(counts, offsets, tmpcur);
  fill_kernel<<<dim3((NE + 255) / 256), dim3(256), 0, stream>>>(edge_index,
                                                                tmpcur, list);
  float* out = (float*)d_out;
  float* out_he = out + (size_t)NN * 40;
  edge_mfma_kernel<<<dim3(NBLK2), dim3(256), 0, stream>>>(
      hn, he, edge_vec, emb, fc1_w1, fc2_w1, edge_index, wb, out_he);
  gather_kernel<<<dim3((NN * 40 + 255) / 256), dim3(256), 0, stream>>>(
      out_he, norm, offsets, counts, list, nf);
  node_kernel<<<dim3((NN + 255) / 256), dim3(256), 0, stream>>>(
      hn, nf, wl1_s, wl1_g, wl1_v, wl2_s, wl2_v, out);
}

// Round 12
// 161.637 us; speedup vs baseline: 1.4300x; 1.2117x over previous
//
#include <hip/hip_runtime.h>
#include <hip/hip_bf16.h>
#include <math.h>

#define NN 10000
#define NE 100000
#define NBLK2 ((NE + 63) / 64)   // 1563 blocks, 64 edges (4 waves x 16)

typedef __attribute__((ext_vector_type(4))) float f32x4;
typedef __attribute__((ext_vector_type(8))) short short8;

static constexpr float C_TANH  = 1.5927f;
static constexpr float SQ3     = 1.7320508075688772f;
static constexpr float H_SCALE = 0.4472135954999579f;   // C_RELU/sqrt(10)
static constexpr float A0Q   = 0.11785113019775793f * 0.25f;  // sqrt(1/72)/4
static constexpr float A0S3Q = 0.06804138174397717f * 0.25f;  // sqrt(1/216)/4
static constexpr float B0Q   = 0.20412414523193154f * 0.25f;  // sqrt(1/24)/4
static constexpr float B0S3Q = 0.11785113019775793f * 0.25f;  // sqrt(1/72)/4
static constexpr float S32 = 0.1767766952966369f;
static constexpr float S16 = 0.25f;
static constexpr float S8  = 0.3535533905932738f;

__device__ __forceinline__ unsigned short f2bf(float f) {
  union { float f; unsigned u; } cv; cv.f = f;
  unsigned r = cv.u + 0x7fffu + ((cv.u >> 16) & 1u);
  return (unsigned short)(r >> 16);
}
__device__ __forceinline__ float bf2f(unsigned short s) {
  return __uint_as_float(((unsigned)s) << 16);
}

// ---------------------------------------------------------------------------
// prep (blocks [0,28)) + hist (blocks [28,419)) fused: one launch.
// ---------------------------------------------------------------------------
__global__ void prep_hist_kernel(const float* __restrict__ fc1_w2,
                                 const float* __restrict__ fc2_w2,
                                 unsigned short* __restrict__ wb,
                                 const int* __restrict__ edge_index,
                                 int* __restrict__ counts) {
  if (blockIdx.x >= 28) {
    int e = (blockIdx.x - 28) * 256 + threadIdx.x;
    if (e < NE) atomicAdd(&counts[edge_index[NE + e]], 1);
    return;
  }
  int t = blockIdx.x * 256 + threadIdx.x;   // t < 7168 = 112*64
  int lane = t & 63, blk = t >> 6;
  int grp = lane >> 4, c = lane & 15;
  unsigned short* dst = wb + (size_t)blk * 512 + lane * 8;
  int gemm, s, nt;
  if (blk < 72)       { gemm = 0; s = blk >> 1;        nt = blk & 1; }
  else if (blk < 84)  { gemm = 1; s = blk - 72;        nt = 0; }
  else if (blk < 108) { gemm = 2; s = (blk - 84) >> 1; nt = (blk - 84) & 1; }
  else                { gemm = 3; s = blk - 108;       nt = 0; }
  int n = nt * 16 + c;
  #pragma unroll
  for (int j = 0; j < 8; ++j) {
    int K = 32 * s + grp * 8 + j;
    int u = K >> 4, k = K & 15;
    float v = 0.f;
    if (gemm == 0) {
      if (n < 16) v = (u < 48) ? A0Q   * fc1_w2[k * 2304 + u * 16 + n]
                               : A0S3Q * fc1_w2[k * 2304 + 1152 + (u - 48) * 16 + n];
      else if (n < 24) { int w = n - 16;
        v = (u < 48) ? A0Q   * fc1_w2[k * 2304 + 768 + u * 8 + w]
                     : A0S3Q * fc1_w2[k * 2304 + 1536 + (u - 48) * 8 + w];
      } else { int w = n - 24;
        v = (u < 48) ? A0Q * fc1_w2[k * 2304 + 1728 + u * 8 + w] : 0.f;
      }
    } else if (gemm == 1) {
      v = (n < 8) ? A0Q * fc1_w2[k * 2304 + 2112 + u * 8 + n] : 0.f;
    } else if (gemm == 2) {
      if (u < 16) {
        if (n < 16)      v = B0Q * fc2_w2[k * 576 + u * 16 + n];
        else if (n < 24) v = B0Q * fc2_w2[k * 576 + 384 + u * 8 + (n - 16)];
      } else {
        if (n < 16)      v = B0S3Q * fc2_w2[k * 576 + 256 + (u - 16) * 16 + n];
      }
    } else {
      v = (n < 8) ? B0Q * fc2_w2[k * 576 + 512 + u * 8 + n] : 0.f;
    }
    dst[j] = f2bf(v);
  }
}

// single-block exclusive scan over counts[NN] -> offsets, tmpcur
__global__ void scan_kernel(const int* __restrict__ counts,
                            int* __restrict__ offsets,
                            int* __restrict__ tmpcur) {
  __shared__ int partial[256];
  int i = threadIdx.x;
  int base = i * 40;
  int loc = 0;
  for (int j = 0; j < 40; ++j) {
    int idx = base + j;
    if (idx < NN) loc += counts[idx];
  }
  partial[i] = loc;
  __syncthreads();
  if (i == 0) {
    int run = 0;
    for (int k = 0; k < 256; ++k) { int t = partial[k]; partial[k] = run; run += t; }
  }
  __syncthreads();
  int acc = partial[i];
  for (int j = 0; j < 40; ++j) {
    int idx = base + j;
    if (idx < NN) {
      offsets[idx] = acc;
      tmpcur[idx] = acc;
      acc += counts[idx];
    }
  }
}

__global__ void fill_kernel(const int* __restrict__ edge_index,
                            int* __restrict__ tmpcur, int* __restrict__ list) {
  int e = blockIdx.x * blockDim.x + threadIdx.x;
  if (e >= NE) return;
  int d = edge_index[NE + e];
  int slot = atomicAdd(&tmpcur[d], 1);
  list[slot] = e;
}

// A-fragment: 8 bf16 products x*h[k0+j], packed pairs
__device__ __forceinline__ short8 mk_afrag(float x, const float* hh) {
  union { short8 s8; __hip_bfloat162 h2[4]; } u;
  #pragma unroll
  for (int m = 0; m < 4; ++m)
    u.h2[m] = __float22bfloat162_rn(make_float2(x * hh[2 * m], x * hh[2 * m + 1]));
  return u.s8;
}

// ---------------------------------------------------------------------------
// Edge kernel: r10-VERIFIED body, verbatim (LDS OUT1/OUT2 flush, dedicated
// regions, 4 waves x 16 edges). Bisection: r11's in-register G/J refactor is
// reverted; if this round passes, that refactor was the r11 bug.
// ---------------------------------------------------------------------------
#define XS1_OFF  0        // ushort [16][74]  (xs 48 | xvs 24, pad 2)
#define XV1_OFF  2368     // ushort [16][74]  ([i][24]: he8|src8|dst8)
#define H1_OFF   4736     // float  [16][17]
#define H2_OFF   5824     // float  [16][17]
#define SH_OFF   6912     // float  [16][4]
#define X2S_OFF  7168     // ushort [16][26]  (tmp_s 16 | tmpvs 8, pad 2)
#define X2V_OFF  8000     // ushort [16][26]  ([i][8])
#define OUT1_OFF 8832     // float  [16][57]  DEDICATED (no overlay)
#define OUT2_OFF 12480    // float  [16][49]  DEDICATED (no overlay)
#define SLICE    15616
#define SMEM_BYTES (4 * SLICE)

__global__ __launch_bounds__(256, 2) void edge_mfma_kernel(
    const float* __restrict__ hn, const float* __restrict__ he,
    const float* __restrict__ edge_vec, const float* __restrict__ emb,
    const float* __restrict__ fc1_w1, const float* __restrict__ fc2_w1,
    const int* __restrict__ edge_index, const unsigned short* __restrict__ wb,
    float* __restrict__ out_he) {
  __shared__ __align__(16) char smem[SMEM_BYTES];
  const int tid = threadIdx.x;
  const int wv = tid >> 6, l = tid & 63;
  char* sw = smem + wv * SLICE;
  unsigned short* XS1u = (unsigned short*)(sw + XS1_OFF);
  unsigned short* XV1u = (unsigned short*)(sw + XV1_OFF);
  float* H1f = (float*)(sw + H1_OFF);
  float* H2f = (float*)(sw + H2_OFF);
  float* SHf = (float*)(sw + SH_OFF);
  unsigned short* X2Su = (unsigned short*)(sw + X2S_OFF);
  unsigned short* X2Vu = (unsigned short*)(sw + X2V_OFF);
  float* OUT1f = (float*)(sw + OUT1_OFF);
  float* OUT2f = (float*)(sw + OUT2_OFF);

  const int e4 = l >> 2, part = l & 3;       // staging/epilogue mapping
  const int c = l & 15, grp = l >> 4;        // GEMM mapping
  const int k0 = (grp & 1) * 8;
  const int du = grp >> 1;
  const int e = blockIdx.x * 64 + wv * 16 + e4;
  const int eld = (e < NE) ? e : (NE - 1);
  const short8* wbv = (const short8*)wb;

  // ---------- A: stage raw rows ----------
  {
    const float* her = he + (size_t)eld * 40;
    int srcn = edge_index[eld], dstn = edge_index[NE + eld];
    const float* hsr = hn + (size_t)srcn * 40;
    const float* hdr = hn + (size_t)dstn * 40;
    #pragma unroll
    for (int q = 0; q < 10; ++q) {
      int idx = part * 10 + q;
      float vee = her[idx], vs = hsr[idx], vd = hdr[idx];
      if (idx < 16) {
        XS1u[e4 * 74 + idx]      = f2bf(vee);
        XS1u[e4 * 74 + 16 + idx] = f2bf(vs);
        XS1u[e4 * 74 + 32 + idx] = f2bf(vd);
      } else {
        int m = idx - 16, up = m / 3, i = m % 3;
        XV1u[e4 * 74 + i * 24 + up]      = f2bf(vee);
        XV1u[e4 * 74 + i * 24 + 8 + up]  = f2bf(vs);
        XV1u[e4 * 74 + i * 24 + 16 + up] = f2bf(vd);
      }
    }
    if (part == 3) {
      float ev0 = edge_vec[eld * 3 + 0], ev1 = edge_vec[eld * 3 + 1],
            ev2 = edge_vec[eld * 3 + 2];
      float rn = rsqrtf(fmaf(ev0, ev0, fmaf(ev1, ev1, ev2 * ev2)));
      SHf[e4 * 4 + 0] = SQ3 * ev1 * rn;
      SHf[e4 * 4 + 1] = SQ3 * ev2 * rn;
      SHf[e4 * 4 + 2] = SQ3 * ev0 * rn;
    }
  }
  float em[10];
  #pragma unroll
  for (int m = 0; m < 10; ++m) em[m] = emb[(size_t)eld * 10 + m];
  __syncthreads();

  // ---------- C: derived (h1,h2 from em; xvs from XV1+SH) ----------
  {
    #pragma unroll
    for (int kk = 0; kk < 4; ++kk) {
      int k = part * 4 + kk;
      float s1 = 0.f, s2 = 0.f;
      #pragma unroll
      for (int m = 0; m < 10; ++m) {
        s1 = fmaf(em[m], fc1_w1[m * 16 + k], s1);
        s2 = fmaf(em[m], fc2_w1[m * 16 + k], s2);
      }
      H1f[e4 * 17 + k] = s1 > 0.f ? s1 * H_SCALE : 0.f;
      H2f[e4 * 17 + k] = s2 > 0.f ? s2 * H_SCALE : 0.f;
    }
    #pragma unroll
    for (int uu = 0; uu < 6; ++uu) {
      int us = part * 6 + uu;
      float a = 0.f;
      #pragma unroll
      for (int i = 0; i < 3; ++i)
        a = fmaf(bf2f(XV1u[e4 * 74 + i * 24 + us]), SHf[e4 * 4 + i], a);
      XS1u[e4 * 74 + 48 + us] = f2bf(a);
    }
  }
  __syncthreads();

  // ---------- E: layer-1 GEMMs (B from global) ----------
  float hh[8];
  #pragma unroll
  for (int j = 0; j < 8; ++j) hh[j] = H1f[c * 17 + k0 + j];

  f32x4 accA0 = {0.f, 0.f, 0.f, 0.f}, accA1 = {0.f, 0.f, 0.f, 0.f};
  #pragma unroll 6
  for (int s = 0; s < 36; ++s) {
    float x = bf2f(XS1u[c * 74 + 2 * s + du]);
    short8 a = mk_afrag(x, hh);
    short8 b0 = wbv[(size_t)(s * 2 + 0) * 64 + l];
    short8 b1 = wbv[(size_t)(s * 2 + 1) * 64 + l];
    accA0 = __builtin_amdgcn_mfma_f32_16x16x32_bf16(a, b0, accA0, 0, 0, 0);
    accA1 = __builtin_amdgcn_mfma_f32_16x16x32_bf16(a, b1, accA1, 0, 0, 0);
  }
  f32x4 accB0 = {0.f, 0.f, 0.f, 0.f}, accB1 = {0.f, 0.f, 0.f, 0.f},
        accB2 = {0.f, 0.f, 0.f, 0.f};
  #pragma unroll 4
  for (int s = 0; s < 12; ++s) {
    short8 b = wbv[(size_t)(72 + s) * 64 + l];
    float x0 = bf2f(XV1u[c * 74 + 0 * 24 + 2 * s + du]);
    float x1 = bf2f(XV1u[c * 74 + 1 * 24 + 2 * s + du]);
    float x2 = bf2f(XV1u[c * 74 + 2 * 24 + 2 * s + du]);
    accB0 = __builtin_amdgcn_mfma_f32_16x16x32_bf16(mk_afrag(x0, hh), b, accB0, 0, 0, 0);
    accB1 = __builtin_amdgcn_mfma_f32_16x16x32_bf16(mk_afrag(x1, hh), b, accB1, 0, 0, 0);
    accB2 = __builtin_amdgcn_mfma_f32_16x16x32_bf16(mk_afrag(x2, hh), b, accB2, 0, 0, 0);
  }
  __syncthreads();

  // ---------- F: flush layer-1 D-frags (D: col=l&15, row=(l>>4)*4+r) ----------
  #pragma unroll
  for (int r = 0; r < 4; ++r) {
    int eo = grp * 4 + r;
    OUT1f[eo * 57 + c]      = accA0[r];
    OUT1f[eo * 57 + 16 + c] = accA1[r];   // [16,24)=out_g, [24,32)=svw
    if (c < 8) {
      OUT1f[eo * 57 + 32 + c * 3 + 0] = accB0[r];
      OUT1f[eo * 57 + 32 + c * 3 + 1] = accB1[r];
      OUT1f[eo * 57 + 32 + c * 3 + 2] = accB2[r];
    }
  }
  __syncthreads();

  // ---------- G: nonlinearity -> layer-2 inputs ----------
  {
    #pragma unroll
    for (int j = 0; j < 4; ++j) {
      int wch = part * 4 + j;
      X2Su[e4 * 26 + wch] = f2bf(C_TANH * tanhf(OUT1f[e4 * 57 + wch]));
    }
    #pragma unroll
    for (int j = 0; j < 2; ++j) {
      int w = part * 2 + j;
      float g  = C_TANH * tanhf(OUT1f[e4 * 57 + 16 + w]);
      float sv = OUT1f[e4 * 57 + 24 + w];
      float tvs = 0.f;
      #pragma unroll
      for (int i = 0; i < 3; ++i) {
        float tv = g * fmaf(SHf[e4 * 4 + i], sv, OUT1f[e4 * 57 + 32 + w * 3 + i]);
        X2Vu[e4 * 26 + i * 8 + w] = f2bf(tv);
        tvs = fmaf(SHf[e4 * 4 + i], tv, tvs);
      }
      X2Su[e4 * 26 + 16 + w] = f2bf(tvs);
    }
  }
  __syncthreads();

  // ---------- H: layer-2 GEMMs ----------
  #pragma unroll
  for (int j = 0; j < 8; ++j) hh[j] = H2f[c * 17 + k0 + j];
  f32x4 accC0 = {0.f, 0.f, 0.f, 0.f}, accC1 = {0.f, 0.f, 0.f, 0.f};
  #pragma unroll 4
  for (int s = 0; s < 12; ++s) {
    float x = bf2f(X2Su[c * 26 + 2 * s + du]);
    short8 a = mk_afrag(x, hh);
    short8 b0 = wbv[(size_t)(84 + s * 2 + 0) * 64 + l];
    short8 b1 = wbv[(size_t)(84 + s * 2 + 1) * 64 + l];
    accC0 = __builtin_amdgcn_mfma_f32_16x16x32_bf16(a, b0, accC0, 0, 0, 0);
    accC1 = __builtin_amdgcn_mfma_f32_16x16x32_bf16(a, b1, accC1, 0, 0, 0);
  }
  f32x4 accD0 = {0.f, 0.f, 0.f, 0.f}, accD1 = {0.f, 0.f, 0.f, 0.f},
        accD2 = {0.f, 0.f, 0.f, 0.f};
  #pragma unroll
  for (int s = 0; s < 4; ++s) {
    short8 b = wbv[(size_t)(108 + s) * 64 + l];
    float x0 = bf2f(X2Vu[c * 26 + 0 * 8 + 2 * s + du]);
    float x1 = bf2f(X2Vu[c * 26 + 1 * 8 + 2 * s + du]);
    float x2 = bf2f(X2Vu[c * 26 + 2 * 8 + 2 * s + du]);
    accD0 = __builtin_amdgcn_mfma_f32_16x16x32_bf16(mk_afrag(x0, hh), b, accD0, 0, 0, 0);
    accD1 = __builtin_amdgcn_mfma_f32_16x16x32_bf16(mk_afrag(x1, hh), b, accD1, 0, 0, 0);
    accD2 = __builtin_amdgcn_mfma_f32_16x16x32_bf16(mk_afrag(x2, hh), b, accD2, 0, 0, 0);
  }
  __syncthreads();

  // ---------- I: flush layer-2 ----------
  #pragma unroll
  for (int r = 0; r < 4; ++r) {
    int eo = grp * 4 + r;
    OUT2f[eo * 49 + c] = accC0[r];
    if (c < 8) {
      OUT2f[eo * 49 + 16 + c] = accC1[r];
      OUT2f[eo * 49 + 24 + c * 3 + 0] = accD0[r];
      OUT2f[eo * 49 + 24 + c * 3 + 1] = accD1[r];
      OUT2f[eo * 49 + 24 + c * 3 + 2] = accD2[r];
    }
  }
  __syncthreads();

  // ---------- J: epilogue (plain stores; gather handles the segment-sum) ----
  if (e < NE) {
    const float* her = he + (size_t)e * 40;
    float* o = out_he + (size_t)e * 40;
    #pragma unroll
    for (int q = 0; q < 10; ++q) {
      int j = part * 10 + q;
      float val;
      if (j < 16) {
        val = her[j] + OUT2f[e4 * 49 + j];
      } else {
        int m = j - 16, w = m / 3, i = m % 3;
        val = her[j] + fmaf(SHf[e4 * 4 + i], OUT2f[e4 * 49 + 16 + w],
                            OUT2f[e4 * 49 + 24 + w * 3 + i]);
      }
      o[j] = val;
    }
  }
}

// ---------------------------------------------------------------------------
// Fused gather+node: one WAVE per node (unchanged from r11).
// ---------------------------------------------------------------------------
__global__ __launch_bounds__(256) void gnode_kernel(
    const float* __restrict__ hn, const float* __restrict__ he_new,
    const float* __restrict__ norm, const int* __restrict__ offsets,
    const int* __restrict__ counts, const int* __restrict__ list,
    const float* __restrict__ wl1_s, const float* __restrict__ wl1_g,
    const float* __restrict__ wl1_v, const float* __restrict__ wl2_s,
    const float* __restrict__ wl2_v, float* __restrict__ out) {
  __shared__ float rhs[4][40];
  __shared__ float nfs[4][40];
  __shared__ float gbuf[4][48];
  const int wv = threadIdx.x >> 6, lane = threadIdx.x & 63;
  const int n = blockIdx.x * 4 + wv;   // 2500 blocks x 4 = NN exactly

  if (lane < 40) {
    rhs[wv][lane] = hn[(size_t)n * 40 + lane];
    int b = offsets[n], cnt = counts[n];
    long long acc = 0;
    for (int k = 0; k < cnt; ++k) {
      int e = list[b + k];
      double p = (double)he_new[(size_t)e * 40 + lane] * (double)norm[e];
      acc += (long long)llrint(p * 4294967296.0);
    }
    nfs[wv][lane] = (float)((double)acc * 2.3283064365386963e-10);
  }
  __syncthreads();

  if (lane < 16) {
    int w = lane;
    float a = 0.f;
    #pragma unroll
    for (int u = 0; u < 32; ++u) {
      float x = (u < 16) ? rhs[wv][u] : nfs[wv][u - 16];
      a = fmaf(x, wl1_s[u * 16 + w], a);
    }
    gbuf[wv][w] = C_TANH * tanhf(a * S32);
  } else if (lane < 24) {
    int w = lane - 16;
    float a = 0.f;
    #pragma unroll
    for (int u = 0; u < 32; ++u) {
      float x = (u < 16) ? rhs[wv][u] : nfs[wv][u - 16];
      a = fmaf(x, wl1_g[u * 8 + w], a);
    }
    gbuf[wv][16 + w] = C_TANH * tanhf(a * S32);
  } else if (lane < 48) {
    int m = lane - 24, w = m / 3, i = m - w * 3;
    float a = 0.f;
    #pragma unroll
    for (int u = 0; u < 16; ++u) {
      float x = (u < 8) ? rhs[wv][16 + u * 3 + i] : nfs[wv][16 + (u - 8) * 3 + i];
      a = fmaf(x, wl1_v[u * 8 + w], a);
    }
    gbuf[wv][24 + m] = a;   // raw l1v
  }
  __syncthreads();

  if (lane < 16) {
    int v = lane;
    float a = 0.f;
    #pragma unroll
    for (int w = 0; w < 16; ++w) a = fmaf(gbuf[wv][w], wl2_s[w * 16 + v], a);
    out[(size_t)n * 40 + v] = rhs[wv][v] + a * S16;
  } else if (lane < 40) {
    int m = lane - 16, v = m / 3, i = m - v * 3;
    float a = 0.f;
    #pragma unroll
    for (int w = 0; w < 8; ++w) {
      float gv = gbuf[wv][16 + w] * gbuf[wv][24 + w * 3 + i] * S16;
      a = fmaf(gv, wl2_v[w * 8 + v], a);
    }
    out[(size_t)n * 40 + 16 + m] = rhs[wv][16 + m] + a * S8;
  }
}

extern "C" void kernel_launch(void* const* d_in, const int* in_sizes, int n_in,
                              void* d_out, int out_size, void* d_ws,
                              size_t ws_size, hipStream_t stream) {
  const float* hn       = (const float*)d_in[0];
  const float* he       = (const float*)d_in[1];
  const float* edge_vec = (const float*)d_in[2];
  const float* emb      = (const float*)d_in[3];
  const float* norm     = (const float*)d_in[4];
  const float* fc1_w1   = (const float*)d_in[5];
  const float* fc1_w2   = (const float*)d_in[6];
  const float* fc2_w1   = (const float*)d_in[7];
  const float* fc2_w2   = (const float*)d_in[8];
  const float* wl1_s    = (const float*)d_in[9];
  const float* wl1_g    = (const float*)d_in[10];
  const float* wl1_v    = (const float*)d_in[11];
  const float* wl2_s    = (const float*)d_in[12];
  const float* wl2_v    = (const float*)d_in[13];
  const int*   edge_index = (const int*)d_in[14];

  char* ws = (char*)d_ws;
  unsigned short* wb = (unsigned short*)ws;          // [0, 114688) blobs
  int* counts  = (int*)(ws + 131072);                // 10K int
  int* offsets = (int*)(ws + 171072);                // 10K int
  int* tmpcur  = (int*)(ws + 211072);                // 10K int
  int* list    = (int*)(ws + 251072);                // 100K int

  hipMemsetAsync(counts, 0, NN * sizeof(int), stream);
  prep_hist_kernel<<<dim3(28 + (NE + 255) / 256), dim3(256), 0, stream>>>(
      fc1_w2, fc2_w2, wb, edge_index, counts);
  scan_kernel<<<dim3(1), dim3(256), 0, stream>>>(counts, offsets, tmpcur);
  fill_kernel<<<dim3((NE + 255) / 256), dim3(256), 0, stream>>>(edge_index,
                                                                tmpcur, list);
  float* out = (float*)d_out;
  float* out_he = out + (size_t)NN * 40;
  edge_mfma_kernel<<<dim3(NBLK2), dim3(256), 0, stream>>>(
      hn, he, edge_vec, emb, fc1_w1, fc2_w1, edge_index, wb, out_he);
  gnode_kernel<<<dim3(NN / 4), dim3(256), 0, stream>>>(
      hn, out_he, norm, offsets, counts, list, wl1_s, wl1_g, wl1_v, wl2_s,
      wl2_v, out);
}

// Round 17
// 161.012 us; speedup vs baseline: 1.4356x; 1.0039x over previous
//
#include <hip/hip_runtime.h>
#include <hip/hip_bf16.h>
#include <math.h>

#define NN 10000
#define NE 100000
#define NBLK2 ((NE + 63) / 64)   // 1563 blocks, 64 edges (4 waves x 16)

typedef __attribute__((ext_vector_type(4))) float f32x4;
typedef __attribute__((ext_vector_type(8))) short short8;

static constexpr float C_TANH  = 1.5927f;
static constexpr float SQ3     = 1.7320508075688772f;
static constexpr float H_SCALE = 0.4472135954999579f;   // C_RELU/sqrt(10)
static constexpr float A0Q   = 0.11785113019775793f * 0.25f;  // sqrt(1/72)/4
static constexpr float A0S3Q = 0.06804138174397717f * 0.25f;  // sqrt(1/216)/4
static constexpr float B0Q   = 0.20412414523193154f * 0.25f;  // sqrt(1/24)/4
static constexpr float B0S3Q = 0.11785113019775793f * 0.25f;  // sqrt(1/72)/4
static constexpr float S32 = 0.1767766952966369f;
static constexpr float S16 = 0.25f;
static constexpr float S8  = 0.3535533905932738f;

__device__ __forceinline__ unsigned short f2bf(float f) {
  union { float f; unsigned u; } cv; cv.f = f;
  unsigned r = cv.u + 0x7fffu + ((cv.u >> 16) & 1u);
  return (unsigned short)(r >> 16);
}
__device__ __forceinline__ float bf2f(unsigned short s) {
  return __uint_as_float(((unsigned)s) << 16);
}

// ---------------------------------------------------------------------------
// prep (blocks [0,28)) + hist (blocks [28,419)) fused: one launch.
// ---------------------------------------------------------------------------
__global__ void prep_hist_kernel(const float* __restrict__ fc1_w2,
                                 const float* __restrict__ fc2_w2,
                                 unsigned short* __restrict__ wb,
                                 const int* __restrict__ edge_index,
                                 int* __restrict__ counts) {
  if (blockIdx.x >= 28) {
    int e = (blockIdx.x - 28) * 256 + threadIdx.x;
    if (e < NE) atomicAdd(&counts[edge_index[NE + e]], 1);
    return;
  }
  int t = blockIdx.x * 256 + threadIdx.x;   // t < 7168 = 112*64
  int lane = t & 63, blk = t >> 6;
  int grp = lane >> 4, c = lane & 15;
  unsigned short* dst = wb + (size_t)blk * 512 + lane * 8;
  int gemm, s, nt;
  if (blk < 72)       { gemm = 0; s = blk >> 1;        nt = blk & 1; }
  else if (blk < 84)  { gemm = 1; s = blk - 72;        nt = 0; }
  else if (blk < 108) { gemm = 2; s = (blk - 84) >> 1; nt = (blk - 84) & 1; }
  else                { gemm = 3; s = blk - 108;       nt = 0; }
  int n = nt * 16 + c;
  #pragma unroll
  for (int j = 0; j < 8; ++j) {
    int K = 32 * s + grp * 8 + j;
    int u = K >> 4, k = K & 15;
    float v = 0.f;
    if (gemm == 0) {
      if (n < 16) v = (u < 48) ? A0Q   * fc1_w2[k * 2304 + u * 16 + n]
                               : A0S3Q * fc1_w2[k * 2304 + 1152 + (u - 48) * 16 + n];
      else if (n < 24) { int w = n - 16;
        v = (u < 48) ? A0Q   * fc1_w2[k * 2304 + 768 + u * 8 + w]
                     : A0S3Q * fc1_w2[k * 2304 + 1536 + (u - 48) * 8 + w];
      } else { int w = n - 24;
        v = (u < 48) ? A0Q * fc1_w2[k * 2304 + 1728 + u * 8 + w] : 0.f;
      }
    } else if (gemm == 1) {
      v = (n < 8) ? A0Q * fc1_w2[k * 2304 + 2112 + u * 8 + n] : 0.f;
    } else if (gemm == 2) {
      if (u < 16) {
        if (n < 16)      v = B0Q * fc2_w2[k * 576 + u * 16 + n];
        else if (n < 24) v = B0Q * fc2_w2[k * 576 + 384 + u * 8 + (n - 16)];
      } else {
        if (n < 16)      v = B0S3Q * fc2_w2[k * 576 + 256 + (u - 16) * 16 + n];
      }
    } else {
      v = (n < 8) ? B0Q * fc2_w2[k * 576 + 512 + u * 8 + n] : 0.f;
    }
    dst[j] = f2bf(v);
  }
}

// single-block exclusive scan over counts[NN] -> offsets, tmpcur
__global__ void scan_kernel(const int* __restrict__ counts,
                            int* __restrict__ offsets,
                            int* __restrict__ tmpcur) {
  __shared__ int partial[256];
  int i = threadIdx.x;
  int base = i * 40;
  int loc = 0;
  for (int j = 0; j < 40; ++j) {
    int idx = base + j;
    if (idx < NN) loc += counts[idx];
  }
  partial[i] = loc;
  __syncthreads();
  if (i == 0) {
    int run = 0;
    for (int k = 0; k < 256; ++k) { int t = partial[k]; partial[k] = run; run += t; }
  }
  __syncthreads();
  int acc = partial[i];
  for (int j = 0; j < 40; ++j) {
    int idx = base + j;
    if (idx < NN) {
      offsets[idx] = acc;
      tmpcur[idx] = acc;
      acc += counts[idx];
    }
  }
}

__global__ void fill_kernel(const int* __restrict__ edge_index,
                            int* __restrict__ tmpcur, int* __restrict__ list) {
  int e = blockIdx.x * blockDim.x + threadIdx.x;
  if (e >= NE) return;
  int d = edge_index[NE + e];
  int slot = atomicAdd(&tmpcur[d], 1);
  list[slot] = e;
}

// A-fragment: 8 bf16 products x*h[k0+j], packed pairs
__device__ __forceinline__ short8 mk_afrag(float x, const float* hh) {
  union { short8 s8; __hip_bfloat162 h2[4]; } u;
  #pragma unroll
  for (int m = 0; m < 4; ++m)
    u.h2[m] = __float22bfloat162_rn(make_float2(x * hh[2 * m], x * hh[2 * m + 1]));
  return u.s8;
}

// ---------------------------------------------------------------------------
// Edge kernel: r12-VERIFIED body, verbatim (LDS OUT1/OUT2 flush, dedicated
// regions, 4 waves x 16 edges). Bisection: r11's in-register G/J refactor is
// reverted; if this round passes, that refactor was the r11 bug.
// ---------------------------------------------------------------------------
#define XS1_OFF  0        // ushort [16][74]  (xs 48 | xvs 24, pad 2)
#define XV1_OFF  2368     // ushort [16][74]  ([i][24]: he8|src8|dst8)
#define H1_OFF   4736     // float  [16][17]
#define H2_OFF   5824     // float  [16][17]
#define SH_OFF   6912     // float  [16][4]
#define X2S_OFF  7168     // ushort [16][26]  (tmp_s 16 | tmpvs 8, pad 2)
#define X2V_OFF  8000     // ushort [16][26]  ([i][8])
#define OUT1_OFF 8832     // float  [16][57]  DEDICATED (no overlay)
#define OUT2_OFF 12480    // float  [16][49]  DEDICATED (no overlay)
#define SLICE    15616
#define SMEM_BYTES (4 * SLICE)

__global__ __launch_bounds__(256, 2) void edge_mfma_kernel(
    const float* __restrict__ hn, const float* __restrict__ he,
    const float* __restrict__ edge_vec, const float* __restrict__ emb,
    const float* __restrict__ fc1_w1, const float* __restrict__ fc2_w1,
    const int* __restrict__ edge_index, const unsigned short* __restrict__ wb,
    float* __restrict__ out_he) {
  __shared__ __align__(16) char smem[SMEM_BYTES];
  const int tid = threadIdx.x;
  const int wv = tid >> 6, l = tid & 63;
  char* sw = smem + wv * SLICE;
  unsigned short* XS1u = (unsigned short*)(sw + XS1_OFF);
  unsigned short* XV1u = (unsigned short*)(sw + XV1_OFF);
  float* H1f = (float*)(sw + H1_OFF);
  float* H2f = (float*)(sw + H2_OFF);
  float* SHf = (float*)(sw + SH_OFF);
  unsigned short* X2Su = (unsigned short*)(sw + X2S_OFF);
  unsigned short* X2Vu = (unsigned short*)(sw + X2V_OFF);
  float* OUT1f = (float*)(sw + OUT1_OFF);
  float* OUT2f = (float*)(sw + OUT2_OFF);

  const int e4 = l >> 2, part = l & 3;       // staging/epilogue mapping
  const int c = l & 15, grp = l >> 4;        // GEMM mapping
  const int k0 = (grp & 1) * 8;
  const int du = grp >> 1;
  const int e = blockIdx.x * 64 + wv * 16 + e4;
  const int eld = (e < NE) ? e : (NE - 1);
  const short8* wbv = (const short8*)wb;

  // ---------- A: stage raw rows ----------
  {
    const float* her = he + (size_t)eld * 40;
    int srcn = edge_index[eld], dstn = edge_index[NE + eld];
    const float* hsr = hn + (size_t)srcn * 40;
    const float* hdr = hn + (size_t)dstn * 40;
    #pragma unroll
    for (int q = 0; q < 10; ++q) {
      int idx = part * 10 + q;
      float vee = her[idx], vs = hsr[idx], vd = hdr[idx];
      if (idx < 16) {
        XS1u[e4 * 74 + idx]      = f2bf(vee);
        XS1u[e4 * 74 + 16 + idx] = f2bf(vs);
        XS1u[e4 * 74 + 32 + idx] = f2bf(vd);
      } else {
        int m = idx - 16, up = m / 3, i = m % 3;
        XV1u[e4 * 74 + i * 24 + up]      = f2bf(vee);
        XV1u[e4 * 74 + i * 24 + 8 + up]  = f2bf(vs);
        XV1u[e4 * 74 + i * 24 + 16 + up] = f2bf(vd);
      }
    }
    if (part == 3) {
      float ev0 = edge_vec[eld * 3 + 0], ev1 = edge_vec[eld * 3 + 1],
            ev2 = edge_vec[eld * 3 + 2];
      float rn = rsqrtf(fmaf(ev0, ev0, fmaf(ev1, ev1, ev2 * ev2)));
      SHf[e4 * 4 + 0] = SQ3 * ev1 * rn;
      SHf[e4 * 4 + 1] = SQ3 * ev2 * rn;
      SHf[e4 * 4 + 2] = SQ3 * ev0 * rn;
    }
  }
  float em[10];
  #pragma unroll
  for (int m = 0; m < 10; ++m) em[m] = emb[(size_t)eld * 10 + m];
  __syncthreads();

  // ---------- C: derived (h1,h2 from em; xvs from XV1+SH) ----------
  {
    #pragma unroll
    for (int kk = 0; kk < 4; ++kk) {
      int k = part * 4 + kk;
      float s1 = 0.f, s2 = 0.f;
      #pragma unroll
      for (int m = 0; m < 10; ++m) {
        s1 = fmaf(em[m], fc1_w1[m * 16 + k], s1);
        s2 = fmaf(em[m], fc2_w1[m * 16 + k], s2);
      }
      H1f[e4 * 17 + k] = s1 > 0.f ? s1 * H_SCALE : 0.f;
      H2f[e4 * 17 + k] = s2 > 0.f ? s2 * H_SCALE : 0.f;
    }
    #pragma unroll
    for (int uu = 0; uu < 6; ++uu) {
      int us = part * 6 + uu;
      float a = 0.f;
      #pragma unroll
      for (int i = 0; i < 3; ++i)
        a = fmaf(bf2f(XV1u[e4 * 74 + i * 24 + us]), SHf[e4 * 4 + i], a);
      XS1u[e4 * 74 + 48 + us] = f2bf(a);
    }
  }
  __syncthreads();

  // ---------- E: layer-1 GEMMs (B from global) ----------
  float hh[8];
  #pragma unroll
  for (int j = 0; j < 8; ++j) hh[j] = H1f[c * 17 + k0 + j];

  f32x4 accA0 = {0.f, 0.f, 0.f, 0.f}, accA1 = {0.f, 0.f, 0.f, 0.f};
  #pragma unroll 6
  for (int s = 0; s < 36; ++s) {
    float x = bf2f(XS1u[c * 74 + 2 * s + du]);
    short8 a = mk_afrag(x, hh);
    short8 b0 = wbv[(size_t)(s * 2 + 0) * 64 + l];
    short8 b1 = wbv[(size_t)(s * 2 + 1) * 64 + l];
    accA0 = __builtin_amdgcn_mfma_f32_16x16x32_bf16(a, b0, accA0, 0, 0, 0);
    accA1 = __builtin_amdgcn_mfma_f32_16x16x32_bf16(a, b1, accA1, 0, 0, 0);
  }
  f32x4 accB0 = {0.f, 0.f, 0.f, 0.f}, accB1 = {0.f, 0.f, 0.f, 0.f},
        accB2 = {0.f, 0.f, 0.f, 0.f};
  #pragma unroll 4
  for (int s = 0; s < 12; ++s) {
    short8 b = wbv[(size_t)(72 + s) * 64 + l];
    float x0 = bf2f(XV1u[c * 74 + 0 * 24 + 2 * s + du]);
    float x1 = bf2f(XV1u[c * 74 + 1 * 24 + 2 * s + du]);
    float x2 = bf2f(XV1u[c * 74 + 2 * 24 + 2 * s + du]);
    accB0 = __builtin_amdgcn_mfma_f32_16x16x32_bf16(mk_afrag(x0, hh), b, accB0, 0, 0, 0);
    accB1 = __builtin_amdgcn_mfma_f32_16x16x32_bf16(mk_afrag(x1, hh), b, accB1, 0, 0, 0);
    accB2 = __builtin_amdgcn_mfma_f32_16x16x32_bf16(mk_afrag(x2, hh), b, accB2, 0, 0, 0);
  }
  __syncthreads();

  // ---------- F: flush layer-1 D-frags (D: col=l&15, row=(l>>4)*4+r) ----------
  #pragma unroll
  for (int r = 0; r < 4; ++r) {
    int eo = grp * 4 + r;
    OUT1f[eo * 57 + c]      = accA0[r];
    OUT1f[eo * 57 + 16 + c] = accA1[r];   // [16,24)=out_g, [24,32)=svw
    if (c < 8) {
      OUT1f[eo * 57 + 32 + c * 3 + 0] = accB0[r];
      OUT1f[eo * 57 + 32 + c * 3 + 1] = accB1[r];
      OUT1f[eo * 57 + 32 + c * 3 + 2] = accB2[r];
    }
  }
  __syncthreads();

  // ---------- G: nonlinearity -> layer-2 inputs ----------
  {
    #pragma unroll
    for (int j = 0; j < 4; ++j) {
      int wch = part * 4 + j;
      X2Su[e4 * 26 + wch] = f2bf(C_TANH * tanhf(OUT1f[e4 * 57 + wch]));
    }
    #pragma unroll
    for (int j = 0; j < 2; ++j) {
      int w = part * 2 + j;
      float g  = C_TANH * tanhf(OUT1f[e4 * 57 + 16 + w]);
      float sv = OUT1f[e4 * 57 + 24 + w];
      float tvs = 0.f;
      #pragma unroll
      for (int i = 0; i < 3; ++i) {
        float tv = g * fmaf(SHf[e4 * 4 + i], sv, OUT1f[e4 * 57 + 32 + w * 3 + i]);
        X2Vu[e4 * 26 + i * 8 + w] = f2bf(tv);
        tvs = fmaf(SHf[e4 * 4 + i], tv, tvs);
      }
      X2Su[e4 * 26 + 16 + w] = f2bf(tvs);
    }
  }
  __syncthreads();

  // ---------- H: layer-2 GEMMs ----------
  #pragma unroll
  for (int j = 0; j < 8; ++j) hh[j] = H2f[c * 17 + k0 + j];
  f32x4 accC0 = {0.f, 0.f, 0.f, 0.f}, accC1 = {0.f, 0.f, 0.f, 0.f};
  #pragma unroll 4
  for (int s = 0; s < 12; ++s) {
    float x = bf2f(X2Su[c * 26 + 2 * s + du]);
    short8 a = mk_afrag(x, hh);
    short8 b0 = wbv[(size_t)(84 + s * 2 + 0) * 64 + l];
    short8 b1 = wbv[(size_t)(84 + s * 2 + 1) * 64 + l];
    accC0 = __builtin_amdgcn_mfma_f32_16x16x32_bf16(a, b0, accC0, 0, 0, 0);
    accC1 = __builtin_amdgcn_mfma_f32_16x16x32_bf16(a, b1, accC1, 0, 0, 0);
  }
  f32x4 accD0 = {0.f, 0.f, 0.f, 0.f}, accD1 = {0.f, 0.f, 0.f, 0.f},
        accD2 = {0.f, 0.f, 0.f, 0.f};
  #pragma unroll
  for (int s = 0; s < 4; ++s) {
    short8 b = wbv[(size_t)(108 + s) * 64 + l];
    float x0 = bf2f(X2Vu[c * 26 + 0 * 8 + 2 * s + du]);
    float x1 = bf2f(X2Vu[c * 26 + 1 * 8 + 2 * s + du]);
    float x2 = bf2f(X2Vu[c * 26 + 2 * 8 + 2 * s + du]);
    accD0 = __builtin_amdgcn_mfma_f32_16x16x32_bf16(mk_afrag(x0, hh), b, accD0, 0, 0, 0);
    accD1 = __builtin_amdgcn_mfma_f32_16x16x32_bf16(mk_afrag(x1, hh), b, accD1, 0, 0, 0);
    accD2 = __builtin_amdgcn_mfma_f32_16x16x32_bf16(mk_afrag(x2, hh), b, accD2, 0, 0, 0);
  }
  __syncthreads();

  // ---------- I: flush layer-2 ----------
  #pragma unroll
  for (int r = 0; r < 4; ++r) {
    int eo = grp * 4 + r;
    OUT2f[eo * 49 + c] = accC0[r];
    if (c < 8) {
      OUT2f[eo * 49 + 16 + c] = accC1[r];
      OUT2f[eo * 49 + 24 + c * 3 + 0] = accD0[r];
      OUT2f[eo * 49 + 24 + c * 3 + 1] = accD1[r];
      OUT2f[eo * 49 + 24 + c * 3 + 2] = accD2[r];
    }
  }
  __syncthreads();

  // ---------- J: epilogue (plain stores; gather handles the segment-sum) ----
  if (e < NE) {
    const float* her = he + (size_t)e * 40;
    float* o = out_he + (size_t)e * 40;
    #pragma unroll
    for (int q = 0; q < 10; ++q) {
      int j = part * 10 + q;
      float val;
      if (j < 16) {
        val = her[j] + OUT2f[e4 * 49 + j];
      } else {
        int m = j - 16, w = m / 3, i = m % 3;
        val = her[j] + fmaf(SHf[e4 * 4 + i], OUT2f[e4 * 49 + 16 + w],
                            OUT2f[e4 * 49 + 24 + w * 3 + i]);
      }
      o[j] = val;
    }
  }
}

// ---------------------------------------------------------------------------
// Fused gather+node: one WAVE per node (unchanged from r11).
// ---------------------------------------------------------------------------
__global__ __launch_bounds__(256) void gnode_kernel(
    const float* __restrict__ hn, const float* __restrict__ he_new,
    const float* __restrict__ norm, const int* __restrict__ offsets,
    const int* __restrict__ counts, const int* __restrict__ list,
    const float* __restrict__ wl1_s, const float* __restrict__ wl1_g,
    const float* __restrict__ wl1_v, const float* __restrict__ wl2_s,
    const float* __restrict__ wl2_v, float* __restrict__ out) {
  __shared__ float rhs[4][40];
  __shared__ float nfs[4][40];
  __shared__ float gbuf[4][48];
  const int wv = threadIdx.x >> 6, lane = threadIdx.x & 63;
  const int n = blockIdx.x * 4 + wv;   // 2500 blocks x 4 = NN exactly

  if (lane < 40) {
    rhs[wv][lane] = hn[(size_t)n * 40 + lane];
    int b = offsets[n], cnt = counts[n];
    long long acc = 0;
    for (int k = 0; k < cnt; ++k) {
      int e = list[b + k];
      double p = (double)he_new[(size_t)e * 40 + lane] * (double)norm[e];
      acc += (long long)llrint(p * 4294967296.0);
    }
    nfs[wv][lane] = (float)((double)acc * 2.3283064365386963e-10);
  }
  __syncthreads();

  if (lane < 16) {
    int w = lane;
    float a = 0.f;
    #pragma unroll
    for (int u = 0; u < 32; ++u) {
      float x = (u < 16) ? rhs[wv][u] : nfs[wv][u - 16];
      a = fmaf(x, wl1_s[u * 16 + w], a);
    }
    gbuf[wv][w] = C_TANH * tanhf(a * S32);
  } else if (lane < 24) {
    int w = lane - 16;
    float a = 0.f;
    #pragma unroll
    for (int u = 0; u < 32; ++u) {
      float x = (u < 16) ? rhs[wv][u] : nfs[wv][u - 16];
      a = fmaf(x, wl1_g[u * 8 + w], a);
    }
    gbuf[wv][16 + w] = C_TANH * tanhf(a * S32);
  } else if (lane < 48) {
    int m = lane - 24, w = m / 3, i = m - w * 3;
    float a = 0.f;
    #pragma unroll
    for (int u = 0; u < 16; ++u) {
      float x = (u < 8) ? rhs[wv][16 + u * 3 + i] : nfs[wv][16 + (u - 8) * 3 + i];
      a = fmaf(x, wl1_v[u * 8 + w], a);
    }
    gbuf[wv][24 + m] = a;   // raw l1v
  }
  __syncthreads();

  if (lane < 16) {
    int v = lane;
    float a = 0.f;
    #pragma unroll
    for (int w = 0; w < 16; ++w) a = fmaf(gbuf[wv][w], wl2_s[w * 16 + v], a);
    out[(size_t)n * 40 + v] = rhs[wv][v] + a * S16;
  } else if (lane < 40) {
    int m = lane - 16, v = m / 3, i = m - v * 3;
    float a = 0.f;
    #pragma unroll
    for (int w = 0; w < 8; ++w) {
      float gv = gbuf[wv][16 + w] * gbuf[wv][24 + w * 3 + i] * S16;
      a = fmaf(gv, wl2_v[w * 8 + v], a);
    }
    out[(size_t)n * 40 + 16 + m] = rhs[wv][16 + m] + a * S8;
  }
}

extern "C" void kernel_launch(void* const* d_in, const int* in_sizes, int n_in,
                              void* d_out, int out_size, void* d_ws,
                              size_t ws_size, hipStream_t stream) {
  const float* hn       = (const float*)d_in[0];
  const float* he       = (const float*)d_in[1];
  const float* edge_vec = (const float*)d_in[2];
  const float* emb      = (const float*)d_in[3];
  const float* norm     = (const float*)d_in[4];
  const float* fc1_w1   = (const float*)d_in[5];
  const float* fc1_w2   = (const float*)d_in[6];
  const float* fc2_w1   = (const float*)d_in[7];
  const float* fc2_w2   = (const float*)d_in[8];
  const float* wl1_s    = (const float*)d_in[9];
  const float* wl1_g    = (const float*)d_in[10];
  const float* wl1_v    = (const float*)d_in[11];
  const float* wl2_s    = (const float*)d_in[12];
  const float* wl2_v    = (const float*)d_in[13];
  const int*   edge_index = (const int*)d_in[14];

  char* ws = (char*)d_ws;
  unsigned short* wb = (unsigned short*)ws;          // [0, 114688) blobs
  int* counts  = (int*)(ws + 131072);                // 10K int
  int* offsets = (int*)(ws + 171072);                // 10K int
  int* tmpcur  = (int*)(ws + 211072);                // 10K int
  int* list    = (int*)(ws + 251072);                // 100K int

  hipMemsetAsync(counts, 0, NN * sizeof(int), stream);
  prep_hist_kernel<<<dim3(28 + (NE + 255) / 256), dim3(256), 0, stream>>>(
      fc1_w2, fc2_w2, wb, edge_index, counts);
  scan_kernel<<<dim3(1), dim3(256), 0, stream>>>(counts, offsets, tmpcur);
  fill_kernel<<<dim3((NE + 255) / 256), dim3(256), 0, stream>>>(edge_index,
                                                                tmpcur, list);
  float* out = (float*)d_out;
  float* out_he = out + (size_t)NN * 40;
  edge_mfma_kernel<<<dim3(NBLK2), dim3(256), 0, stream>>>(
      hn, he, edge_vec, emb, fc1_w1, fc2_w1, edge_index, wb, out_he);
  gnode_kernel<<<dim3(NN / 4), dim3(256), 0, stream>>>(
      hn, out_he, norm, offsets, counts, list, wl1_s, wl1_g, wl1_v, wl2_s,
      wl2_v, out);
}